// Round 8
// baseline (363.928 us; speedup 1.0000x reference)
//
#include <hip/hip_runtime.h>
#include <hip/hip_bf16.h>
#include <hip/hip_cooperative_groups.h>

namespace cg = cooperative_groups;

typedef unsigned short u16;
typedef unsigned int u32;
typedef __attribute__((ext_vector_type(8))) short short8;
typedef __attribute__((ext_vector_type(4))) float f32x4;
typedef __attribute__((ext_vector_type(4))) unsigned int u32x4;

__device__ __forceinline__ u16 f2bf(float f) {
    union { float f; unsigned u; } v; v.f = f;
    unsigned r = v.u + 0x7fffu + ((v.u >> 16) & 1u);
    return (u16)(r >> 16);
}

__device__ __forceinline__ float fexp2(float x) {
#if __has_builtin(__builtin_amdgcn_exp2f)
    return __builtin_amdgcn_exp2f(x);
#else
    return __expf(x * 0.6931471805599453f);
#endif
}

// ---------------------------------------------------------------------------
// DPP 16-lane butterfly (r15): masks {1,2,7,15} are GF(2)-independent ->
// valid butterfly over each contiguous 16-lane row.
// ---------------------------------------------------------------------------
template <int CTRL>
__device__ __forceinline__ float fdpp(float x) {
    int xi = __builtin_bit_cast(int, x);
    int r = __builtin_amdgcn_update_dpp(0, xi, CTRL, 0xF, 0xF, true);
    return __builtin_bit_cast(float, r);
}
__device__ __forceinline__ float dpp_max16(float m) {
    m = fmaxf(m, fdpp<0xB1>(m));   // xor 1
    m = fmaxf(m, fdpp<0x4E>(m));   // xor 2
    m = fmaxf(m, fdpp<0x141>(m));  // xor 7 (row_half_mirror)
    m = fmaxf(m, fdpp<0x140>(m));  // xor 15 (row_mirror)
    return m;
}
__device__ __forceinline__ float dpp_sum16(float s) {
    s += fdpp<0xB1>(s);
    s += fdpp<0x4E>(s);
    s += fdpp<0x141>(s);
    s += fdpp<0x140>(s);
    return s;
}

// ---------------------------------------------------------------------------
// fp8 e4m3 pack/unpack (P pre-scaled x256; r9-r13 absmax 0.078).
// ---------------------------------------------------------------------------
#if __has_builtin(__builtin_amdgcn_cvt_pk_fp8_f32) && \
    __has_builtin(__builtin_amdgcn_cvt_f32_fp8)
#define FP8_HW 1
#else
#define FP8_HW 0
#endif

#if !FP8_HW
__device__ __forceinline__ u32 sw_fp8(float x) {  // x in [0, 448]
    union { float f; u32 u; } v; v.f = x;
    int E = (int)(v.u >> 23) - 127;
    if (x < 0.001953125f) return 0;
    if (E < -6) return (u32)(x * 512.0f + 0.5f);
    u32 m = v.u & 0x7fffffu;
    u32 r = (m + 0x80000u) >> 20;
    u32 bits = ((u32)(E + 7) << 3) + r;
    return bits > 0x7eu ? 0x7eu : bits;
}
__device__ __forceinline__ float sw_fp8d(u32 b) {
    u32 e = (b >> 3) & 15u, m = b & 7u;
    if (e == 0) return (float)m * 0.001953125f;
    union { u32 u; float f; } v; v.u = ((e + 120u) << 23) | (m << 20);
    return v.f;
}
#endif

__device__ __forceinline__ u32 fp8x4_pack(float p0, float p1, float p2, float p3) {
#if FP8_HW
    u32 v = (u32)__builtin_amdgcn_cvt_pk_fp8_f32(p0, p1, 0, false);
    v = (u32)__builtin_amdgcn_cvt_pk_fp8_f32(p2, p3, (int)v, true);
    return v;
#else
    return sw_fp8(p0) | (sw_fp8(p1) << 8) | (sw_fp8(p2) << 16) | (sw_fp8(p3) << 24);
#endif
}

#if FP8_HW
#define FP8_DEC(v, s) __builtin_amdgcn_cvt_f32_fp8((int)(v), (s))
#else
#define FP8_DEC(v, s) sw_fp8d(((v) >> ((s) * 8)) & 0xffu)
#endif

// async 16B global->LDS DMA (m97 pattern).
__device__ __forceinline__ void async_cp16(const u16* g, u16* l) {
    __builtin_amdgcn_global_load_lds(
        (const __attribute__((address_space(1))) void*)g,
        (__attribute__((address_space(3))) void*)l, 16, 0, 0);
}

__device__ __forceinline__ short8 mfma_ld(const u16* base, int off) {
    return *(const short8*)&base[off];
}

// ---------------------------------------------------------------------------
// Staging helpers for the 8-phase 256x256 core (T3+T4 schedule).
// ---------------------------------------------------------------------------
__device__ __forceinline__ void stage_half_A(const u16* __restrict__ Q,
                                             u16* dst, int kn, int half,
                                             int wid, int srow, int scol) {
#pragma unroll
    for (int c = 0; c < 2; c++) {
        int win = (wid >> 2) * 16 + half * 8 + (wid & 3) * 2 + c;
        async_cp16(Q + (size_t)(win * 8 + srow) * 512 + kn + scol,
                   dst + win * 512);
    }
}
__device__ __forceinline__ void stage_half_B(const u16* __restrict__ K,
                                             u16* dst, int kn, int half,
                                             int wid, int srow, int scol) {
#pragma unroll
    for (int c = 0; c < 2; c++) {
        int win = (wid >> 1) * 8 + half * 4 + (wid & 1) * 2 + c;
        async_cp16(K + (size_t)(win * 8 + srow) * 512 + kn + scol,
                   dst + win * 512);
    }
}

// ---------------------------------------------------------------------------
// Shared 256x256x512 8-phase core (r20 schedule -- verified optimum of this
// structure; r19 1-barrier and r21 shifted variants both regressed). 8 waves
// (2Mx4N), BK=64, 128 KiB LDS dbuf, counted vmcnt (never 0 in loop):
// half-tiles of kt+1 at A0,B0@p0, B1@p1, A1@p2; waits vmcnt(6)@p1,
// vmcnt(2)@p3. Gray-code phases, register-held B-halves (24 ds_read/kt/wave).
// A.B^T into acc[8][4]; acc (i,j,rg) = C row m0+wm*128+i*16+quad*4+rg,
// col n0+wn*64+j*16+l15.
// ---------------------------------------------------------------------------
__device__ __forceinline__ void core256(const u16* __restrict__ A,
                                        const u16* __restrict__ B,
                                        u16* As0, u16* As1,
                                        u16* Bs0, u16* Bs1,
                                        f32x4 acc[8][4], int tid) {
    int lane = tid & 63, wid = tid >> 6;
    int quad = lane >> 4, l15 = lane & 15;
    int wm = wid >> 2, wn = wid & 3;
    int Gw = lane ^ ((lane >> 3) & 7);
    int srow = Gw >> 3, scol = (Gw & 7) * 8;
    int rl = l15 & 7, winl = l15 >> 3;
    int Pr[2];
#pragma unroll
    for (int h = 0; h < 2; h++)
        Pr[h] = (rl * 8 + ((quad + h * 4) ^ rl)) * 8;

    // Prologue: stage tile 0 fully, single full drain (only one in core).
    stage_half_A(A, As0, 0, 0, wid, srow, scol);
    stage_half_B(B, Bs0, 0, 0, wid, srow, scol);
    stage_half_B(B, Bs0, 0, 1, wid, srow, scol);
    stage_half_A(A, As0, 0, 1, wid, srow, scol);
    asm volatile("s_waitcnt vmcnt(0)" ::: "memory");
    __builtin_amdgcn_s_barrier();
    asm volatile("" ::: "memory");

    for (int kt = 0; kt < 8; ++kt) {
        const u16* Ac = (kt & 1) ? As1 : As0;
        const u16* Bc = (kt & 1) ? Bs1 : Bs0;
        u16* An = (kt & 1) ? As0 : As1;
        u16* Bn = (kt & 1) ? Bs0 : Bs1;
        int kn = (kt + 1) * 64;
        bool pf = (kt < 7);
        short8 af[4][2], bf0[2][2], bf1[2][2];
#pragma unroll
        for (int ph = 0; ph < 4; ++ph) {
            // Gray code: (ih,jh) = (0,0),(0,1),(1,1),(1,0)
            const int ih = ph >> 1;
            const int jh = (ph ^ (ph >> 1)) & 1;
            if (ph == 0) {
#pragma unroll
                for (int h = 0; h < 2; h++)
#pragma unroll
                    for (int ii = 0; ii < 4; ii++)
                        af[ii][h] = mfma_ld(
                            Ac, (wm * 16 + ii * 2 + winl) * 512 + Pr[h]);
#pragma unroll
                for (int h = 0; h < 2; h++)
#pragma unroll
                    for (int jj = 0; jj < 2; jj++)
                        bf0[jj][h] = mfma_ld(
                            Bc, (wn * 8 + jj * 2 + winl) * 512 + Pr[h]);
            } else if (ph == 1) {
#pragma unroll
                for (int h = 0; h < 2; h++)
#pragma unroll
                    for (int jj = 0; jj < 2; jj++)
                        bf1[jj][h] = mfma_ld(
                            Bc, (wn * 8 + 4 + jj * 2 + winl) * 512 + Pr[h]);
            } else if (ph == 2) {
#pragma unroll
                for (int h = 0; h < 2; h++)
#pragma unroll
                    for (int ii = 0; ii < 4; ii++)
                        af[ii][h] = mfma_ld(
                            Ac, (wm * 16 + 8 + ii * 2 + winl) * 512 + Pr[h]);
            }
            if (pf) {
                if (ph == 0) {
                    stage_half_A(A, An, kn, 0, wid, srow, scol);
                    stage_half_B(B, Bn, kn, 0, wid, srow, scol);
                } else if (ph == 1) {
                    stage_half_B(B, Bn, kn, 1, wid, srow, scol);
                } else if (ph == 2) {
                    stage_half_A(A, An, kn, 1, wid, srow, scol);
                }
            }
            if (ph == 1) {
                if (pf) asm volatile("s_waitcnt vmcnt(6)" ::: "memory");
                else    asm volatile("s_waitcnt vmcnt(0)" ::: "memory");
            }
            if (ph == 3) asm volatile("s_waitcnt vmcnt(2)" ::: "memory");
            asm volatile("" ::: "memory");
            __builtin_amdgcn_s_barrier();
            asm volatile("s_waitcnt lgkmcnt(0)" ::: "memory");
            __builtin_amdgcn_s_setprio(1);
            if (jh == 0) {
#pragma unroll
                for (int h = 0; h < 2; h++)
#pragma unroll
                    for (int ii = 0; ii < 4; ii++)
#pragma unroll
                        for (int jj = 0; jj < 2; jj++)
                            acc[ih * 4 + ii][jj] =
                                __builtin_amdgcn_mfma_f32_16x16x32_bf16(
                                    af[ii][h], bf0[jj][h],
                                    acc[ih * 4 + ii][jj], 0, 0, 0);
            } else {
#pragma unroll
                for (int h = 0; h < 2; h++)
#pragma unroll
                    for (int ii = 0; ii < 4; ii++)
#pragma unroll
                        for (int jj = 0; jj < 2; jj++)
                            acc[ih * 4 + ii][2 + jj] =
                                __builtin_amdgcn_mfma_f32_16x16x32_bf16(
                                    af[ii][h], bf1[jj][h],
                                    acc[ih * 4 + ii][2 + jj], 0, 0, 0);
            }
            __builtin_amdgcn_s_setprio(0);
            asm volatile("" ::: "memory");
            __builtin_amdgcn_s_barrier();
            asm volatile("" ::: "memory");
        }
    }
}

// 64x128x512 variant (A 64 rows), 256 "threads" = tid in [0,256).
// NOTE: contains __syncthreads(); when called by two 256-thread halves of a
// 512-thread block, both halves MUST execute it with identical trip counts
// (they do: fixed 8-iteration loop).
__device__ __forceinline__ void gemm512_r64(const u16* __restrict__ A,
                                            const u16* __restrict__ B,
                                            u16* As, u16* Bs,
                                            f32x4 acc[2][4], int tid) {
    const int lane = tid & 63, w = tid >> 6;
    const int quad = lane >> 4, l15 = lane & 15;
    const int wm = tid >> 7, wn = (tid >> 6) & 1;
    const int Gw = lane ^ ((lane >> 3) & 7);
    const int srow = Gw >> 3;
    const int scol = (Gw & 7) * 8;
    const int rl = l15 & 7;
    const int winl = l15 >> 3;
    int Pr[2];
#pragma unroll
    for (int h = 0; h < 2; h++)
        Pr[h] = (rl * 8 + ((quad + h * 4) ^ rl)) * 8;
    const int winA0 = (wm * 32) >> 3, winB0 = (wn * 64) >> 3;
    for (int k0 = 0; k0 < 512; k0 += 64) {
        __syncthreads();
#pragma unroll
        for (int t = 0; t < 2; t++) {
            int win = w * 2 + t;
            async_cp16(A + (size_t)(win * 8 + srow) * 512 + k0 + scol,
                       As + win * 512);
        }
#pragma unroll
        for (int t = 0; t < 4; t++) {
            int win = w * 4 + t;
            async_cp16(B + (size_t)(win * 8 + srow) * 512 + k0 + scol,
                       Bs + win * 512);
        }
        __syncthreads();
#pragma unroll
        for (int h = 0; h < 2; h++) {
            short8 af[2], bfr[4];
#pragma unroll
            for (int i = 0; i < 2; i++)
                af[i] = mfma_ld(As, (winA0 + i * 2 + winl) * 512 + Pr[h]);
#pragma unroll
            for (int j = 0; j < 4; j++)
                bfr[j] = mfma_ld(Bs, (winB0 + j * 2 + winl) * 512 + Pr[h]);
#pragma unroll
            for (int i = 0; i < 2; i++)
#pragma unroll
                for (int j = 0; j < 4; j++)
                    acc[i][j] = __builtin_amdgcn_mfma_f32_16x16x32_bf16(
                        af[i], bfr[j], acc[i][j], 0, 0, 0);
        }
    }
}

// ===========================================================================
// MEGA (r23): the whole pipeline as ONE cooperative kernel.
// r22 diagnostic: +3 launches cost +40.7us (~13.5us/launch) -> with 6
// launches, ~60-90us of the 200us total is launch/dispatch-gap overhead.
// Fusion via grid.sync() removes 5 of 6 launches AND the reduce_stats2
// kernel (cstat recomputed per-block in LDS, 16x redundancy through L2).
// 256 blocks x 512 threads, 1 block/CU (128 KiB arena), 5 stages / 4 syncs:
//   S1 prep (X->bf16 grid-stride; W-transpose 2 units/block as 2x256-thread
//      halves, equal barrier counts; Sg zero by block 0)
//   S2 qkv: 192 tiles on blocks 0..191 (rest idle to sync)
//   S3 attn: 512 tiles, 2 sequential per block (arena reuse safe: core256
//      ends with a full barrier after all LDS reads retired)
//   S4 colsum + fused cstat (per-block rows [mgrp*512, +512) into LDS)
//   S5 final: 512 64x128 tiles, 2 per block via two 256-thread halves
// All accumulation orders identical to the split kernels -> same absmax.
// ===========================================================================
__global__ __launch_bounds__(512, 2) void mega(
    const float* __restrict__ X, const float* __restrict__ W0,
    const float* __restrict__ W1, const float* __restrict__ W2,
    const float* __restrict__ W3, const float* __restrict__ bq,
    const float* __restrict__ bk, const float* __restrict__ bv,
    const float* __restrict__ bo, const float* __restrict__ g,
    const float* __restrict__ bb, const float* __restrict__ mean,
    const float* __restrict__ var, u16* __restrict__ Xb,
    u16* __restrict__ Wqt, u16* __restrict__ Qall,
    float2* __restrict__ statsP, float* __restrict__ Sg,
    u32* __restrict__ Pbuf, float* __restrict__ out) {
    __shared__ __align__(16) u16 arena[65536];  // 128 KiB
    int bid = blockIdx.x, tid = threadIdx.x;
    cg::grid_group grid = cg::this_grid();

    // ---------------- S1: prep ----------------
    {
#pragma unroll
        for (int r = 0; r < 8; r++) {
            int idx4 = bid * 512 + tid + r * 131072;  // 1,048,576 float4s
            float4 v = ((const float4*)X)[idx4];
            ushort4 o;
            o.x = f2bf(v.x); o.y = f2bf(v.y); o.z = f2bf(v.z); o.w = f2bf(v.w);
            ((ushort4*)Xb)[idx4] = o;
        }
        if (bid == 0) {
            float4 z4 = {0.f, 0.f, 0.f, 0.f};
#pragma unroll
            for (int r = 0; r < 4; r++) ((float4*)Sg)[tid + r * 512] = z4;
        }
        int h = tid >> 8, tl = tid & 255;
        int tx = tl & 31, ty = tl >> 5;
        float* fa = (float*)arena;
        float (*tile)[33] = (float(*)[33])(fa + h * 1056);
        for (int u = bid * 2 + h; u < 1024; u += 512) {  // exactly 2 iters/half
            int z = u >> 8, rem = u & 255;
            int bo_ = (rem & 15) * 32, bi = (rem >> 4) * 32;
            const float* src; u16* dst;
            switch (z) {
                case 0: src = W0; dst = Wqt; break;
                case 1: src = W1; dst = Wqt + 262144; break;
                case 2: src = W2; dst = Wqt + 524288; break;
                default: src = W3; dst = Wqt + 786432; break;
            }
#pragma unroll
            for (int s = 0; s < 4; s++)
                tile[ty + s * 8][tx] =
                    src[(size_t)(bi + ty + s * 8) * 512 + bo_ + tx];
            __syncthreads();
#pragma unroll
            for (int s = 0; s < 4; s++)
                dst[(size_t)(bo_ + ty + s * 8) * 512 + bi + tx] =
                    f2bf(tile[tx][ty + s * 8]);
            __syncthreads();  // before tile reuse next iteration
        }
    }
    grid.sync();

    // ---------------- S2: qkv ----------------
    if (bid < 192) {
        int z = bid >> 6, q = bid & 63;
        int m0 = (q >> 1) * 256, n0 = (q & 1) * 256;
        const u16* A = Xb + (size_t)m0 * 512;
        const u16* B = Wqt + (size_t)z * 262144 + (size_t)n0 * 512;
        f32x4 acc[8][4];
#pragma unroll
        for (int i = 0; i < 8; i++)
#pragma unroll
            for (int j = 0; j < 4; j++) acc[i][j] = (f32x4){0.f, 0.f, 0.f, 0.f};
        core256(A, B, arena, arena + 16384, arena + 32768, arena + 49152,
                acc, tid);
        const float* bias = (z == 0) ? bq : (z == 1) ? bk : bv;
        const float qs = (z == 0) ? 1.44269504088896340736f : 1.0f;
        u16* C = Qall + (size_t)z * 4194304;
        int lane = tid & 63, wid = tid >> 6;
        int quad = lane >> 4, l15 = lane & 15;
        int wm = wid >> 2, wn = wid & 3;
#pragma unroll
        for (int j = 0; j < 4; j++) {
            int n = n0 + wn * 64 + j * 16 + l15;
            float bvv = bias[n];
#pragma unroll
            for (int i = 0; i < 8; i++)
#pragma unroll
                for (int rg = 0; rg < 4; rg++) {
                    int m = m0 + wm * 128 + i * 16 + quad * 4 + rg;
                    C[(size_t)m * 512 + n] = f2bf((acc[i][j][rg] + bvv) * qs);
                }
        }
    }
    grid.sync();

    // ---------------- S3: attn pass 1 ----------------
    for (int rr = 0; rr < 2; rr++) {
        int t = bid + rr * 256;
        int mblk = t & 15, nblk = (t >> 4) & 15, b = t >> 8;
        const u16* Q = Qall + ((size_t)(b * 4096 + mblk * 256)) * 512;
        const u16* K = Qall + 4194304 + ((size_t)(b * 4096 + nblk * 256)) * 512;
        f32x4 acc[8][4];
#pragma unroll
        for (int i = 0; i < 8; i++)
#pragma unroll
            for (int j = 0; j < 4; j++) acc[i][j] = (f32x4){0.f, 0.f, 0.f, 0.f};
        core256(Q, K, arena, arena + 16384, arena + 32768, arena + 49152,
                acc, tid);
        int lane = tid & 63, wid = tid >> 6;
        int quad = lane >> 4, l15 = lane & 15;
        int wm = wid >> 2, wn = wid & 3;
        u32* Pt = Pbuf + ((size_t)((b * 16 + mblk) * 16 + nblk)) * 16384;
        int ch = nblk * 4 + wn;
        float2* Sp = statsP + ((size_t)(b * 64 + ch)) * 4096;
        int mbase = mblk * 256 + wm * 128;
#pragma unroll
        for (int i = 0; i < 8; i++) {
            u32x4 pk;
#pragma unroll
            for (int rg = 0; rg < 4; rg++) {
                float v0 = acc[i][0][rg], v1 = acc[i][1][rg];
                float v2 = acc[i][2][rg], v3 = acc[i][3][rg];
                float Mt = fmaxf(fmaxf(v0, v1), fmaxf(v2, v3));
                Mt = dpp_max16(Mt);
                float e8 = Mt - 8.0f;  // x256 pre-scale for fp8 range
                float p0 = fexp2(v0 - e8), p1 = fexp2(v1 - e8);
                float p2 = fexp2(v2 - e8), p3 = fexp2(v3 - e8);
                pk[rg] = fp8x4_pack(p0, p1, p2, p3);
                float L = dpp_sum16(p0 + p1 + p2 + p3);
                if (l15 == 0)
                    Sp[mbase + i * 16 + quad * 4 + rg] =
                        make_float2(Mt, L * 0.00390625f);
            }
            *(u32x4*)&Pt[i * 2048 + tid * 4] = pk;
        }
    }
    grid.sync();

    // ---------------- S4: colsum + fused cstat ----------------
    {
        int nblk = bid & 15, mgrp = (bid >> 4) & 7, b = bid >> 7;
        float* cs = (float*)arena;
        {
            int m = mgrp * 512 + tid;
            const float2* sp = statsP + (size_t)b * 64 * 4096 + m;
            float M = -INFINITY;
#pragma unroll 4
            for (int ch = 0; ch < 64; ch++)
                M = fmaxf(M, sp[(size_t)ch * 4096].x);
            float Z = 0.f;
#pragma unroll 4
            for (int ch = 0; ch < 64; ch++) {
                float2 p = sp[(size_t)ch * 4096];
                Z += p.y * fexp2(p.x - M);
            }
            cs[tid] = M + __log2f(Z);
        }
        __syncthreads();
        int lane = tid & 63, wid = tid >> 6;
        int quad = lane >> 4, l15 = lane & 15;
        int wm = wid >> 2, wn = wid & 3;
        int ch = nblk * 4 + wn;
        const float2* Sp = statsP + ((size_t)(b * 64 + ch)) * 4096;
        float cp[4] = {0.f, 0.f, 0.f, 0.f};
        for (int mb = 0; mb < 2; mb++) {
            int mblk = mgrp * 2 + mb;
            const u32* Pt =
                Pbuf + ((size_t)((b * 16 + mblk) * 16 + nblk)) * 16384;
#pragma unroll
            for (int i = 0; i < 8; i++) {
                int r0 = mblk * 256 + wm * 128 + i * 16 + quad * 4;
                float4 s01 = *(const float4*)&Sp[r0];
                float4 s23 = *(const float4*)&Sp[r0 + 2];
                int rl0 = mb * 256 + wm * 128 + i * 16 + quad * 4;
                float4 cv = *(const float4*)&cs[rl0];
                float fv[4] = {fexp2(s01.x - 8.0f - cv.x),
                               fexp2(s01.z - 8.0f - cv.y),
                               fexp2(s23.x - 8.0f - cv.z),
                               fexp2(s23.z - 8.0f - cv.w)};
                float fm = fmaxf(fmaxf(fv[0], fv[1]), fmaxf(fv[2], fv[3]));
                if (fm > 3.469446951953614e-18f) {  // 2^-58 F-SKIP
                    u32x4 e4 = *(const u32x4*)&Pt[i * 2048 + tid * 4];
#pragma unroll
                    for (int rg = 0; rg < 4; rg++) {
                        u32 e = e4[rg];
                        cp[0] += FP8_DEC(e, 0) * fv[rg];
                        cp[1] += FP8_DEC(e, 1) * fv[rg];
                        cp[2] += FP8_DEC(e, 2) * fv[rg];
                        cp[3] += FP8_DEC(e, 3) * fv[rg];
                    }
                }
            }
        }
#pragma unroll
        for (int j = 0; j < 4; j++) {
            float s = cp[j];
            s += __shfl_xor(s, 16);
            s += __shfl_xor(s, 32);
            if (lane < 16)
                atomicAdd(&Sg[b * 4096 + nblk * 256 + wn * 64 + j * 16 + l15],
                          s);
        }
    }
    grid.sync();

    // ---------------- S5: final ----------------
    {
        int h = tid >> 8, tl = tid & 255;
        int ft = bid * 2 + h;
        int m0 = (ft >> 2) * 64, n0 = (ft & 3) * 128;
        const u16* Vb = Qall + 8388608;
        const u16* Bt = Wqt + 786432;
        u16* As_h = arena + h * 16384;
        u16* Bs_h = arena + 32768 + h * 16384;
        f32x4 acc[2][4];
#pragma unroll
        for (int i = 0; i < 2; i++)
#pragma unroll
            for (int j = 0; j < 4; j++) acc[i][j] = (f32x4){0.f, 0.f, 0.f, 0.f};
        gemm512_r64(Vb + (size_t)m0 * 512, Bt + (size_t)n0 * 512, As_h, Bs_h,
                    acc, tl);
        int lane = tl & 63, quad = lane >> 4, l15 = lane & 15;
        int wm = tl >> 7, wn = (tl >> 6) & 1;
        float sc[2][4];
#pragma unroll
        for (int i = 0; i < 2; i++) {
            float4 s = *(const float4*)&Sg[m0 + wm * 32 + i * 16 + quad * 4];
            float v[4] = {s.x, s.y, s.z, s.w};
#pragma unroll
            for (int rg = 0; rg < 4; rg++) sc[i][rg] = v[rg] / (1e-9f + v[rg]);
        }
#pragma unroll
        for (int j = 0; j < 4; j++) {
            int n = n0 + wn * 64 + j * 16 + l15;
            float aj = rsqrtf(var[n] + 1e-5f) * g[n];
            float cj = bb[n] - mean[n] * aj;
            float bj = bo[n];
#pragma unroll
            for (int i = 0; i < 2; i++)
#pragma unroll
                for (int rg = 0; rg < 4; rg++) {
                    int m = m0 + wm * 32 + i * 16 + quad * 4 + rg;
                    float x = acc[i][j][rg] * sc[i][rg] + bj;
                    float y = x * aj + cj;
                    out[(size_t)m * 512 + n] =
                        fmaxf(y, 0.f) + X[(size_t)m * 512 + n];
                }
        }
    }
}

// ===========================================================================
// Fallback path (r20 kernels) if cooperative launch is unavailable.
// ===========================================================================
__global__ void prep(const float* __restrict__ X, const float* __restrict__ W0,
                     const float* __restrict__ W1, const float* __restrict__ W2,
                     const float* __restrict__ W3, u16* __restrict__ Xb,
                     u16* __restrict__ T0, u16* __restrict__ T1,
                     u16* __restrict__ T2, u16* __restrict__ T3,
                     float* __restrict__ Sg) {
    __shared__ float tile[32][33];
    int id = blockIdx.x, tid = threadIdx.x;
    if (id == 5120) {
        float4 z = {0.f, 0.f, 0.f, 0.f};
#pragma unroll
        for (int t = 0; t < 8; t++) ((float4*)Sg)[tid + t * 256] = z;
        return;
    }
    if (id < 4096) {
        int idx = (id * 256 + tid) * 4;
        float4 v = *(const float4*)&X[idx];
        ushort4 o;
        o.x = f2bf(v.x); o.y = f2bf(v.y); o.z = f2bf(v.z); o.w = f2bf(v.w);
        *(ushort4*)&Xb[idx] = o;
        return;
    }
    int t = id - 4096;
    int z = t >> 8, rem = t & 255;
    int bo_ = (rem & 15) * 32, bi = (rem >> 4) * 32;
    const float* src; u16* dst;
    switch (z) {
        case 0: src = W0; dst = T0; break;
        case 1: src = W1; dst = T1; break;
        case 2: src = W2; dst = T2; break;
        default: src = W3; dst = T3; break;
    }
    int tx = tid & 31, ty = tid >> 5;
#pragma unroll
    for (int s = 0; s < 4; s++) {
        int i = bi + ty + s * 8;
        tile[ty + s * 8][tx] = src[i * 512 + bo_ + tx];
    }
    __syncthreads();
#pragma unroll
    for (int s = 0; s < 4; s++) {
        int o = bo_ + ty + s * 8;
        dst[o * 512 + bi + tx] = f2bf(tile[tx][ty + s * 8]);
    }
}

__global__ __launch_bounds__(512, 2) void gemm_qkv(
    const u16* __restrict__ Xb, const u16* __restrict__ Wall,
    const float* __restrict__ bq, const float* __restrict__ bk,
    const float* __restrict__ bv, u16* __restrict__ Qall) {
    __shared__ __align__(16) u16 As[2][16384];
    __shared__ __align__(16) u16 Bs[2][16384];
    int tid = threadIdx.x;
    int m0 = blockIdx.x * 256, n0 = blockIdx.y * 256, z = blockIdx.z;
    const u16* A = Xb + (size_t)m0 * 512;
    const u16* B = Wall + (size_t)z * 262144 + (size_t)n0 * 512;
    f32x4 acc[8][4];
#pragma unroll
    for (int i = 0; i < 8; i++)
#pragma unroll
        for (int j = 0; j < 4; j++) acc[i][j] = (f32x4){0.f, 0.f, 0.f, 0.f};
    core256(A, B, &As[0][0], &As[1][0], &Bs[0][0], &Bs[1][0], acc, tid);
    const float* bias = (z == 0) ? bq : (z == 1) ? bk : bv;
    const float qs = (z == 0) ? 1.44269504088896340736f : 1.0f;
    u16* C = Qall + (size_t)z * 4194304;
    int lane = tid & 63, wid = tid >> 6;
    int quad = lane >> 4, l15 = lane & 15;
    int wm = wid >> 2, wn = wid & 3;
#pragma unroll
    for (int j = 0; j < 4; j++) {
        int n = n0 + wn * 64 + j * 16 + l15;
        float bvv = bias[n];
#pragma unroll
        for (int i = 0; i < 8; i++)
#pragma unroll
            for (int rg = 0; rg < 4; rg++) {
                int m = m0 + wm * 128 + i * 16 + quad * 4 + rg;
                C[(size_t)m * 512 + n] = f2bf((acc[i][j][rg] + bvv) * qs);
            }
    }
}

__global__ __launch_bounds__(512, 2) void attn_pass1p(
    const u16* __restrict__ Qb, const u16* __restrict__ Kb,
    float2* __restrict__ statsP, u32* __restrict__ Pbuf) {
    __shared__ __align__(16) u16 As[2][16384];
    __shared__ __align__(16) u16 Bs[2][16384];
    int tid = threadIdx.x;
    int mblk = blockIdx.x, nblk = blockIdx.y, b = blockIdx.z;
    const u16* Q = Qb + ((size_t)(b * 4096 + mblk * 256)) * 512;
    const u16* K = Kb + ((size_t)(b * 4096 + nblk * 256)) * 512;
    int lane = tid & 63, wid = tid >> 6;
    int quad = lane >> 4, l15 = lane & 15;
    int wm = wid >> 2, wn = wid & 3;
    f32x4 acc[8][4];
#pragma unroll
    for (int i = 0; i < 8; i++)
#pragma unroll
        for (int j = 0; j < 4; j++) acc[i][j] = (f32x4){0.f, 0.f, 0.f, 0.f};
    core256(Q, K, &As[0][0], &As[1][0], &Bs[0][0], &Bs[1][0], acc, tid);
    u32* Pt = Pbuf + ((size_t)((b * 16 + mblk) * 16 + nblk)) * 16384;
    int ch = nblk * 4 + wn;
    float2* Sp = statsP + ((size_t)(b * 64 + ch)) * 4096;
    int mbase = mblk * 256 + wm * 128;
#pragma unroll
    for (int i = 0; i < 8; i++) {
        u32x4 pk;
#pragma unroll
        for (int rg = 0; rg < 4; rg++) {
            float v0 = acc[i][0][rg], v1 = acc[i][1][rg];
            float v2 = acc[i][2][rg], v3 = acc[i][3][rg];
            float Mt = fmaxf(fmaxf(v0, v1), fmaxf(v2, v3));
            Mt = dpp_max16(Mt);
            float e8 = Mt - 8.0f;
            float p0 = fexp2(v0 - e8), p1 = fexp2(v1 - e8);
            float p2 = fexp2(v2 - e8), p3 = fexp2(v3 - e8);
            pk[rg] = fp8x4_pack(p0, p1, p2, p3);
            float L = dpp_sum16(p0 + p1 + p2 + p3);
            if (l15 == 0)
                Sp[mbase + i * 16 + quad * 4 + rg] =
                    make_float2(Mt, L * 0.00390625f);
        }
        *(u32x4*)&Pt[i * 2048 + tid * 4] = pk;
    }
}

__global__ void reduce_stats2(const float2* __restrict__ statsP,
                              float* __restrict__ cstat) {
    int t = blockIdx.x * 256 + threadIdx.x;
    int b = t >> 12, m = t & 4095;
    const float2* sp = statsP + (size_t)b * 64 * 4096 + m;
    float M = -INFINITY;
#pragma unroll 4
    for (int ch = 0; ch < 64; ch++) M = fmaxf(M, sp[(size_t)ch * 4096].x);
    float Z = 0.f;
#pragma unroll 4
    for (int ch = 0; ch < 64; ch++) {
        float2 p = sp[(size_t)ch * 4096];
        Z += p.y * fexp2(p.x - M);
    }
    cstat[t] = M + __log2f(Z);
}

__global__ __launch_bounds__(512) void colsum(
    const u32* __restrict__ Pbuf, const float2* __restrict__ statsP,
    const float* __restrict__ cstat, float* __restrict__ Sg) {
    int tid = threadIdx.x, lane = tid & 63, wid = tid >> 6;
    int quad = lane >> 4, l15 = lane & 15;
    int wm = wid >> 2, wn = wid & 3;
    int nblk = blockIdx.x, mgrp = blockIdx.y, b = blockIdx.z;
    int ch = nblk * 4 + wn;
    const float2* Sp = statsP + ((size_t)(b * 64 + ch)) * 4096;
    const float* Cp = cstat + (size_t)b * 4096;
    float cp[4] = {0.f, 0.f, 0.f, 0.f};
    for (int mb = 0; mb < 2; mb++) {
        int mblk = mgrp * 2 + mb;
        const u32* Pt =
            Pbuf + ((size_t)((b * 16 + mblk) * 16 + nblk)) * 16384;
#pragma unroll
        for (int i = 0; i < 8; i++) {
            int r0 = mblk * 256 + wm * 128 + i * 16 + quad * 4;
            float4 s01 = *(const float4*)&Sp[r0];
            float4 s23 = *(const float4*)&Sp[r0 + 2];
            float4 cv = *(const float4*)&Cp[r0];
            float fv[4] = {fexp2(s01.x - 8.0f - cv.x),
                           fexp2(s01.z - 8.0f - cv.y),
                           fexp2(s23.x - 8.0f - cv.z),
                           fexp2(s23.z - 8.0f - cv.w)};
            float fm = fmaxf(fmaxf(fv[0], fv[1]), fmaxf(fv[2], fv[3]));
            if (fm > 3.469446951953614e-18f) {
                u32x4 e4 = *(const u32x4*)&Pt[i * 2048 + tid * 4];
#pragma unroll
                for (int rg = 0; rg < 4; rg++) {
                    u32 e = e4[rg];
                    cp[0] += FP8_DEC(e, 0) * fv[rg];
                    cp[1] += FP8_DEC(e, 1) * fv[rg];
                    cp[2] += FP8_DEC(e, 2) * fv[rg];
                    cp[3] += FP8_DEC(e, 3) * fv[rg];
                }
            }
        }
    }
#pragma unroll
    for (int j = 0; j < 4; j++) {
        float s = cp[j];
        s += __shfl_xor(s, 16);
        s += __shfl_xor(s, 32);
        if (lane < 16)
            atomicAdd(&Sg[b * 4096 + nblk * 256 + wn * 64 + j * 16 + l15], s);
    }
}

__global__ __launch_bounds__(256) void gemm_final(
    const u16* __restrict__ A, const u16* __restrict__ Bt,
    const float* __restrict__ Sg, const float* __restrict__ bo,
    const float* __restrict__ g, const float* __restrict__ bb,
    const float* __restrict__ mean, const float* __restrict__ var,
    const float* __restrict__ X, float* __restrict__ out) {
    __shared__ __align__(16) u16 As[4096];
    __shared__ __align__(16) u16 Bs[8192];
    int tid = threadIdx.x;
    int m0 = blockIdx.x * 64, n0 = blockIdx.y * 128;
    f32x4 acc[2][4];
#pragma unroll
    for (int i = 0; i < 2; i++)
#pragma unroll
        for (int j = 0; j < 4; j++) acc[i][j] = (f32x4){0.f, 0.f, 0.f, 0.f};
    gemm512_r64(A + (size_t)m0 * 512, Bt + (size_t)n0 * 512, As, Bs, acc, tid);
    int lane = tid & 63, quad = lane >> 4, l15 = lane & 15;
    int wm = tid >> 7, wn = (tid >> 6) & 1;
    float sc[2][4];
#pragma unroll
    for (int i = 0; i < 2; i++) {
        float4 s = *(const float4*)&Sg[m0 + wm * 32 + i * 16 + quad * 4];
        float v[4] = {s.x, s.y, s.z, s.w};
#pragma unroll
        for (int rg = 0; rg < 4; rg++) sc[i][rg] = v[rg] / (1e-9f + v[rg]);
    }
#pragma unroll
    for (int j = 0; j < 4; j++) {
        int n = n0 + wn * 64 + j * 16 + l15;
        float aj = rsqrtf(var[n] + 1e-5f) * g[n];
        float cj = bb[n] - mean[n] * aj;
        float bj = bo[n];
#pragma unroll
        for (int i = 0; i < 2; i++)
#pragma unroll
            for (int rg = 0; rg < 4; rg++) {
                int m = m0 + wm * 32 + i * 16 + quad * 4 + rg;
                float x = acc[i][j][rg] * sc[i][rg] + bj;
                float y = x * aj + cj;
                out[(size_t)m * 512 + n] = fmaxf(y, 0.f) + X[(size_t)m * 512 + n];
            }
    }
}

// ---------------------------------------------------------------------------
extern "C" void kernel_launch(void* const* d_in, const int* in_sizes, int n_in,
                              void* d_out, int out_size, void* d_ws, size_t ws_size,
                              hipStream_t stream) {
    const float* X  = (const float*)d_in[0];
    const float* Wq = (const float*)d_in[1];
    const float* Wk = (const float*)d_in[2];
    const float* Wv = (const float*)d_in[3];
    const float* Wo = (const float*)d_in[4];
    const float* bq = (const float*)d_in[5];
    const float* bk = (const float*)d_in[6];
    const float* bv = (const float*)d_in[7];
    const float* bo = (const float*)d_in[8];
    const float* g    = (const float*)d_in[9];
    const float* bb   = (const float*)d_in[10];
    const float* mean = (const float*)d_in[11];
    const float* var  = (const float*)d_in[12];
    float* out = (float*)d_out;

    char* ws = (char*)d_ws;
    u16* Xb  = (u16*)(ws + 0);                    // 8 MB
    u16* Wqt = (u16*)(ws + 8388608);              // 4x512KB (Wq,Wk,Wv,Wo) contiguous
    u16* Wot = (u16*)(ws + 9961472);              // == Wqt + 786432
    u16* Qb  = (u16*)(ws + 10485760);             // Q,K,V contiguous 3x8MB
    u16* Kb  = (u16*)(ws + 18874368);
    u16* Vb  = (u16*)(ws + 27262976);
    float2* statsP = (float2*)(ws + 35651584);    // [b][64][4096] f2 = 4 MB
    float* Sg      = (float*)(ws + 39845888);     // 32 KB
    float* cstat   = (float*)(ws + 39878656);     // 32 KB (fallback only)
    u32* Pbuf      = (u32*)(ws + 39911424);       // 32 MB fp8 P

    void* args[] = {&X,  &Wq, &Wk, &Wv, &Wo, &bq, &bk,  &bv, &bo, &g,
                    &bb, &mean, &var, &Xb, &Wqt, &Qb, &statsP, &Sg, &Pbuf, &out};
    hipError_t e = hipLaunchCooperativeKernel((const void*)mega, dim3(256),
                                              dim3(512), args, 0, stream);
    if (e != hipSuccess) {
        // Fallback: r20 six-launch pipeline.
        prep<<<5121, 256, 0, stream>>>(X, Wq, Wk, Wv, Wo, Xb, Wqt,
                                       Wqt + 262144, Wqt + 524288, Wot, Sg);
        gemm_qkv<<<dim3(32, 2, 3), 512, 0, stream>>>(Xb, Wqt, bq, bk, bv, Qb);
        attn_pass1p<<<dim3(16, 16, 2), 512, 0, stream>>>(Qb, Kb, statsP, Pbuf);
        reduce_stats2<<<32, 256, 0, stream>>>(statsP, cstat);
        colsum<<<dim3(16, 8, 2), 512, 0, stream>>>(Pbuf, statsP, cstat, Sg);
        gemm_final<<<dim3(128, 4), 256, 0, stream>>>(Vb, Wot, Sg, bo, g, bb,
                                                     mean, var, X, out);
    }
}

// Round 9
// 203.299 us; speedup vs baseline: 1.7901x; 1.7901x over previous
//
#include <hip/hip_runtime.h>
#include <hip/hip_bf16.h>

typedef unsigned short u16;
typedef unsigned int u32;
typedef __attribute__((ext_vector_type(8))) short short8;
typedef __attribute__((ext_vector_type(4))) float f32x4;
typedef __attribute__((ext_vector_type(4))) unsigned int u32x4;

__device__ __forceinline__ u16 f2bf(float f) {
    union { float f; unsigned u; } v; v.f = f;
    unsigned r = v.u + 0x7fffu + ((v.u >> 16) & 1u);
    return (u16)(r >> 16);
}

__device__ __forceinline__ float fexp2(float x) {
#if __has_builtin(__builtin_amdgcn_exp2f)
    return __builtin_amdgcn_exp2f(x);
#else
    return __expf(x * 0.6931471805599453f);
#endif
}

// ---------------------------------------------------------------------------
// DPP 16-lane butterfly (r15): masks {1,2,7,15} are GF(2)-independent ->
// valid butterfly over each contiguous 16-lane row.
// ---------------------------------------------------------------------------
template <int CTRL>
__device__ __forceinline__ float fdpp(float x) {
    int xi = __builtin_bit_cast(int, x);
    int r = __builtin_amdgcn_update_dpp(0, xi, CTRL, 0xF, 0xF, true);
    return __builtin_bit_cast(float, r);
}
__device__ __forceinline__ float dpp_max16(float m) {
    m = fmaxf(m, fdpp<0xB1>(m));   // xor 1
    m = fmaxf(m, fdpp<0x4E>(m));   // xor 2
    m = fmaxf(m, fdpp<0x141>(m));  // xor 7 (row_half_mirror)
    m = fmaxf(m, fdpp<0x140>(m));  // xor 15 (row_mirror)
    return m;
}
__device__ __forceinline__ float dpp_sum16(float s) {
    s += fdpp<0xB1>(s);
    s += fdpp<0x4E>(s);
    s += fdpp<0x141>(s);
    s += fdpp<0x140>(s);
    return s;
}

// ---------------------------------------------------------------------------
// fp8 e4m3 pack/unpack (P pre-scaled x256; r9-r13 absmax 0.078).
// ---------------------------------------------------------------------------
#if __has_builtin(__builtin_amdgcn_cvt_pk_fp8_f32) && \
    __has_builtin(__builtin_amdgcn_cvt_f32_fp8)
#define FP8_HW 1
#else
#define FP8_HW 0
#endif

#if !FP8_HW
__device__ __forceinline__ u32 sw_fp8(float x) {  // x in [0, 448]
    union { float f; u32 u; } v; v.f = x;
    int E = (int)(v.u >> 23) - 127;
    if (x < 0.001953125f) return 0;
    if (E < -6) return (u32)(x * 512.0f + 0.5f);
    u32 m = v.u & 0x7fffffu;
    u32 r = (m + 0x80000u) >> 20;
    u32 bits = ((u32)(E + 7) << 3) + r;
    return bits > 0x7eu ? 0x7eu : bits;
}
__device__ __forceinline__ float sw_fp8d(u32 b) {
    u32 e = (b >> 3) & 15u, m = b & 7u;
    if (e == 0) return (float)m * 0.001953125f;
    union { u32 u; float f; } v; v.u = ((e + 120u) << 23) | (m << 20);
    return v.f;
}
#endif

__device__ __forceinline__ u32 fp8x4_pack(float p0, float p1, float p2, float p3) {
#if FP8_HW
    u32 v = (u32)__builtin_amdgcn_cvt_pk_fp8_f32(p0, p1, 0, false);
    v = (u32)__builtin_amdgcn_cvt_pk_fp8_f32(p2, p3, (int)v, true);
    return v;
#else
    return sw_fp8(p0) | (sw_fp8(p1) << 8) | (sw_fp8(p2) << 16) | (sw_fp8(p3) << 24);
#endif
}

#if FP8_HW
#define FP8_DEC(v, s) __builtin_amdgcn_cvt_f32_fp8((int)(v), (s))
#else
#define FP8_DEC(v, s) sw_fp8d(((v) >> ((s) * 8)) & 0xffu)
#endif

// async 16B global->LDS DMA (m97 pattern).
__device__ __forceinline__ void async_cp16(const u16* g, u16* l) {
    __builtin_amdgcn_global_load_lds(
        (const __attribute__((address_space(1))) void*)g,
        (__attribute__((address_space(3))) void*)l, 16, 0, 0);
}

__device__ __forceinline__ short8 mfma_ld(const u16* base, int off) {
    return *(const short8*)&base[off];
}

// ---------------------------------------------------------------------------
// Staging helpers for the 8-phase 256x256 core (T3+T4 schedule).
// Half-tiles: A-half(ih) = wins wm'*16 + ih*8 + [0,8); B-half(jh) = wins
// wn'*8 + jh*4 + [0,4). Each wave stages 2 wins (1 KiB each) per half.
// LDS dest is wave-uniform base + lane*16 (global_load_lds constraint);
// the XOR swizzle lives in the per-lane GLOBAL source address (m173 pattern).
// ---------------------------------------------------------------------------
__device__ __forceinline__ void stage_half_A(const u16* __restrict__ Q,
                                             u16* dst, int kn, int half,
                                             int wid, int srow, int scol) {
#pragma unroll
    for (int c = 0; c < 2; c++) {
        int win = (wid >> 2) * 16 + half * 8 + (wid & 3) * 2 + c;
        async_cp16(Q + (size_t)(win * 8 + srow) * 512 + kn + scol,
                   dst + win * 512);
    }
}
__device__ __forceinline__ void stage_half_B(const u16* __restrict__ K,
                                             u16* dst, int kn, int half,
                                             int wid, int srow, int scol) {
#pragma unroll
    for (int c = 0; c < 2; c++) {
        int win = (wid >> 1) * 8 + half * 4 + (wid & 1) * 2 + c;
        async_cp16(K + (size_t)(win * 8 + srow) * 512 + kn + scol,
                   dst + win * 512);
    }
}

// ---------------------------------------------------------------------------
// Shared 256x256x512 8-phase core (r20 schedule -- the verified optimum of
// this structure across the session's experiments: r19 1-barrier regressed
// (convoys, 52->65us), r21 shifted-pipeline regressed (+112 VGPR live
// fragments -> ~9MB/dispatch scratch spill, 47.8->49.5us), r23 cooperative
// mega regressed (grid.sync serialization + idle stages, 262us). 8 waves
// (2Mx4N), BK=64, 128 KiB LDS dbuf, counted vmcnt (never 0 in loop):
// half-tiles of kt+1 at A0,B0@p0, B1@p1, A1@p2; waits vmcnt(6)@p1,
// vmcnt(2)@p3. Gray-code phases, register-held B-halves (24 ds_read/kt/wave).
// A.B^T into acc[8][4]; acc (i,j,rg) = C row m0+wm*128+i*16+quad*4+rg,
// col n0+wn*64+j*16+l15. Operating point: ~716 TF effective (attn 48us for
// 34.4 GF), MfmaUtil ~27% -- consistent with the guide's 2-wave/SIMD
// 256^2 structure-ceiling band.
// ---------------------------------------------------------------------------
__device__ __forceinline__ void core256(const u16* __restrict__ A,
                                        const u16* __restrict__ B,
                                        u16* As0, u16* As1,
                                        u16* Bs0, u16* Bs1,
                                        f32x4 acc[8][4], int tid) {
    int lane = tid & 63, wid = tid >> 6;
    int quad = lane >> 4, l15 = lane & 15;
    int wm = wid >> 2, wn = wid & 3;
    int Gw = lane ^ ((lane >> 3) & 7);
    int srow = Gw >> 3, scol = (Gw & 7) * 8;
    int rl = l15 & 7, winl = l15 >> 3;
    int Pr[2];
#pragma unroll
    for (int h = 0; h < 2; h++)
        Pr[h] = (rl * 8 + ((quad + h * 4) ^ rl)) * 8;

    // Prologue: stage tile 0 fully, single full drain (only one in core).
    stage_half_A(A, As0, 0, 0, wid, srow, scol);
    stage_half_B(B, Bs0, 0, 0, wid, srow, scol);
    stage_half_B(B, Bs0, 0, 1, wid, srow, scol);
    stage_half_A(A, As0, 0, 1, wid, srow, scol);
    asm volatile("s_waitcnt vmcnt(0)" ::: "memory");
    __builtin_amdgcn_s_barrier();
    asm volatile("" ::: "memory");

    for (int kt = 0; kt < 8; ++kt) {
        const u16* Ac = (kt & 1) ? As1 : As0;
        const u16* Bc = (kt & 1) ? Bs1 : Bs0;
        u16* An = (kt & 1) ? As0 : As1;
        u16* Bn = (kt & 1) ? Bs0 : Bs1;
        int kn = (kt + 1) * 64;
        bool pf = (kt < 7);
        short8 af[4][2], bf0[2][2], bf1[2][2];
#pragma unroll
        for (int ph = 0; ph < 4; ++ph) {
            // Gray code: (ih,jh) = (0,0),(0,1),(1,1),(1,0)
            const int ih = ph >> 1;
            const int jh = (ph ^ (ph >> 1)) & 1;
            if (ph == 0) {
#pragma unroll
                for (int h = 0; h < 2; h++)
#pragma unroll
                    for (int ii = 0; ii < 4; ii++)
                        af[ii][h] = mfma_ld(
                            Ac, (wm * 16 + ii * 2 + winl) * 512 + Pr[h]);
#pragma unroll
                for (int h = 0; h < 2; h++)
#pragma unroll
                    for (int jj = 0; jj < 2; jj++)
                        bf0[jj][h] = mfma_ld(
                            Bc, (wn * 8 + jj * 2 + winl) * 512 + Pr[h]);
            } else if (ph == 1) {
#pragma unroll
                for (int h = 0; h < 2; h++)
#pragma unroll
                    for (int jj = 0; jj < 2; jj++)
                        bf1[jj][h] = mfma_ld(
                            Bc, (wn * 8 + 4 + jj * 2 + winl) * 512 + Pr[h]);
            } else if (ph == 2) {
#pragma unroll
                for (int h = 0; h < 2; h++)
#pragma unroll
                    for (int ii = 0; ii < 4; ii++)
                        af[ii][h] = mfma_ld(
                            Ac, (wm * 16 + 8 + ii * 2 + winl) * 512 + Pr[h]);
            }
            if (pf) {
                if (ph == 0) {
                    stage_half_A(A, An, kn, 0, wid, srow, scol);
                    stage_half_B(B, Bn, kn, 0, wid, srow, scol);
                } else if (ph == 1) {
                    stage_half_B(B, Bn, kn, 1, wid, srow, scol);
                } else if (ph == 2) {
                    stage_half_A(A, An, kn, 1, wid, srow, scol);
                }
            }
            if (ph == 1) {
                if (pf) asm volatile("s_waitcnt vmcnt(6)" ::: "memory");
                else    asm volatile("s_waitcnt vmcnt(0)" ::: "memory");
            }
            if (ph == 3) asm volatile("s_waitcnt vmcnt(2)" ::: "memory");
            asm volatile("" ::: "memory");
            __builtin_amdgcn_s_barrier();
            asm volatile("s_waitcnt lgkmcnt(0)" ::: "memory");
            __builtin_amdgcn_s_setprio(1);
            if (jh == 0) {
#pragma unroll
                for (int h = 0; h < 2; h++)
#pragma unroll
                    for (int ii = 0; ii < 4; ii++)
#pragma unroll
                        for (int jj = 0; jj < 2; jj++)
                            acc[ih * 4 + ii][jj] =
                                __builtin_amdgcn_mfma_f32_16x16x32_bf16(
                                    af[ii][h], bf0[jj][h],
                                    acc[ih * 4 + ii][jj], 0, 0, 0);
            } else {
#pragma unroll
                for (int h = 0; h < 2; h++)
#pragma unroll
                    for (int ii = 0; ii < 4; ii++)
#pragma unroll
                        for (int jj = 0; jj < 2; jj++)
                            acc[ih * 4 + ii][2 + jj] =
                                __builtin_amdgcn_mfma_f32_16x16x32_bf16(
                                    af[ii][h], bf1[jj][h],
                                    acc[ih * 4 + ii][2 + jj], 0, 0, 0);
            }
            __builtin_amdgcn_s_setprio(0);
            asm volatile("" ::: "memory");
            __builtin_amdgcn_s_barrier();
            asm volatile("" ::: "memory");
        }
    }
}

// 64x128x512 variant (A 64 rows). As: 4096 u16, Bs: 8192 u16.
__device__ __forceinline__ void gemm512_r64(const u16* __restrict__ A,
                                            const u16* __restrict__ B,
                                            u16* As, u16* Bs,
                                            f32x4 acc[2][4], int tid) {
    const int lane = tid & 63, w = tid >> 6;
    const int quad = lane >> 4, l15 = lane & 15;
    const int wm = tid >> 7, wn = (tid >> 6) & 1;
    const int Gw = lane ^ ((lane >> 3) & 7);
    const int srow = Gw >> 3;
    const int scol = (Gw & 7) * 8;
    const int rl = l15 & 7;
    const int winl = l15 >> 3;
    int Pr[2];
#pragma unroll
    for (int h = 0; h < 2; h++)
        Pr[h] = (rl * 8 + ((quad + h * 4) ^ rl)) * 8;
    const int winA0 = (wm * 32) >> 3, winB0 = (wn * 64) >> 3;
    for (int k0 = 0; k0 < 512; k0 += 64) {
        __syncthreads();
#pragma unroll
        for (int t = 0; t < 2; t++) {
            int win = w * 2 + t;
            async_cp16(A + (size_t)(win * 8 + srow) * 512 + k0 + scol,
                       As + win * 512);
        }
#pragma unroll
        for (int t = 0; t < 4; t++) {
            int win = w * 4 + t;
            async_cp16(B + (size_t)(win * 8 + srow) * 512 + k0 + scol,
                       Bs + win * 512);
        }
        __syncthreads();
#pragma unroll
        for (int h = 0; h < 2; h++) {
            short8 af[2], bfr[4];
#pragma unroll
            for (int i = 0; i < 2; i++)
                af[i] = mfma_ld(As, (winA0 + i * 2 + winl) * 512 + Pr[h]);
#pragma unroll
            for (int j = 0; j < 4; j++)
                bfr[j] = mfma_ld(Bs, (winB0 + j * 2 + winl) * 512 + Pr[h]);
#pragma unroll
            for (int i = 0; i < 2; i++)
#pragma unroll
                for (int j = 0; j < 4; j++)
                    acc[i][j] = __builtin_amdgcn_mfma_f32_16x16x32_bf16(
                        af[i], bfr[j], acc[i][j], 0, 0, 0);
        }
    }
}

// ---------------------------------------------------------------------------
// Fused prep: [0,4096) convert X->bf16; [4096,5120) transpose weights;
// 5120: zero Sg (per-launch, graph-safe).
// ---------------------------------------------------------------------------
__global__ void prep(const float* __restrict__ X, const float* __restrict__ W0,
                     const float* __restrict__ W1, const float* __restrict__ W2,
                     const float* __restrict__ W3, u16* __restrict__ Xb,
                     u16* __restrict__ T0, u16* __restrict__ T1,
                     u16* __restrict__ T2, u16* __restrict__ T3,
                     float* __restrict__ Sg) {
    __shared__ float tile[32][33];
    int id = blockIdx.x, tid = threadIdx.x;
    if (id == 5120) {
        float4 z = {0.f, 0.f, 0.f, 0.f};
#pragma unroll
        for (int t = 0; t < 8; t++) ((float4*)Sg)[tid + t * 256] = z;
        return;
    }
    if (id < 4096) {
        int idx = (id * 256 + tid) * 4;
        float4 v = *(const float4*)&X[idx];
        ushort4 o;
        o.x = f2bf(v.x); o.y = f2bf(v.y); o.z = f2bf(v.z); o.w = f2bf(v.w);
        *(ushort4*)&Xb[idx] = o;
        return;
    }
    int t = id - 4096;
    int z = t >> 8, rem = t & 255;
    int bo_ = (rem & 15) * 32, bi = (rem >> 4) * 32;
    const float* src; u16* dst;
    switch (z) {
        case 0: src = W0; dst = T0; break;
        case 1: src = W1; dst = T1; break;
        case 2: src = W2; dst = T2; break;
        default: src = W3; dst = T3; break;
    }
    int tx = tid & 31, ty = tid >> 5;
#pragma unroll
    for (int s = 0; s < 4; s++) {
        int i = bi + ty + s * 8;
        tile[ty + s * 8][tx] = src[i * 512 + bo_ + tx];
    }
    __syncthreads();
#pragma unroll
    for (int s = 0; s < 4; s++) {
        int o = bo_ + ty + s * 8;
        dst[o * 512 + bi + tx] = f2bf(tile[tx][ty + s * 8]);
    }
}

// ---------------------------------------------------------------------------
// Fused QKV projection (256x256 8-phase core). Grid (32, 2, 3), 512 threads.
// z==0 (Q) scaled by log2(e) -> base-2 score domain.
// ---------------------------------------------------------------------------
__global__ __launch_bounds__(512, 2) void gemm_qkv(
    const u16* __restrict__ Xb, const u16* __restrict__ Wall,
    const float* __restrict__ bq, const float* __restrict__ bk,
    const float* __restrict__ bv, u16* __restrict__ Qall) {
    __shared__ __align__(16) u16 As[2][16384];
    __shared__ __align__(16) u16 Bs[2][16384];
    int tid = threadIdx.x;
    int m0 = blockIdx.x * 256, n0 = blockIdx.y * 256, z = blockIdx.z;
    const u16* A = Xb + (size_t)m0 * 512;
    const u16* B = Wall + (size_t)z * 262144 + (size_t)n0 * 512;
    f32x4 acc[8][4];
#pragma unroll
    for (int i = 0; i < 8; i++)
#pragma unroll
        for (int j = 0; j < 4; j++) acc[i][j] = (f32x4){0.f, 0.f, 0.f, 0.f};
    core256(A, B, &As[0][0], &As[1][0], &Bs[0][0], &Bs[1][0], acc, tid);

    const float* bias = (z == 0) ? bq : (z == 1) ? bk : bv;
    const float qs = (z == 0) ? 1.44269504088896340736f : 1.0f;
    u16* C = Qall + (size_t)z * 4194304;
    int lane = tid & 63, wid = tid >> 6;
    int quad = lane >> 4, l15 = lane & 15;
    int wm = wid >> 2, wn = wid & 3;
#pragma unroll
    for (int j = 0; j < 4; j++) {
        int n = n0 + wn * 64 + j * 16 + l15;
        float bvv = bias[n];
#pragma unroll
        for (int i = 0; i < 8; i++)
#pragma unroll
            for (int rg = 0; rg < 4; rg++) {
                int m = m0 + wm * 128 + i * 16 + quad * 4 + rg;
                C[(size_t)m * 512 + n] = f2bf((acc[i][j][rg] + bvv) * qs);
            }
    }
}

// ---------------------------------------------------------------------------
// Pass 1 (256x256 8-phase core + softmax epilogue). Epilogue: per (i,rg)
// row, chunk-max over 64 cols via DPP butterfly, P = exp2(s - Mt + 8) fp8x4
// in Pbuf[i][tid][rg] (dwordx4), stats (Mt, L/256).
// Grid (16, 16, 2), 512 threads.
// ---------------------------------------------------------------------------
__global__ __launch_bounds__(512, 2) void attn_pass1p(
    const u16* __restrict__ Qb, const u16* __restrict__ Kb,
    float2* __restrict__ statsP, u32* __restrict__ Pbuf) {
    __shared__ __align__(16) u16 As[2][16384];
    __shared__ __align__(16) u16 Bs[2][16384];
    int tid = threadIdx.x;
    int mblk = blockIdx.x, nblk = blockIdx.y, b = blockIdx.z;
    const u16* Q = Qb + ((size_t)(b * 4096 + mblk * 256)) * 512;
    const u16* K = Kb + ((size_t)(b * 4096 + nblk * 256)) * 512;
    int lane = tid & 63, wid = tid >> 6;
    int quad = lane >> 4, l15 = lane & 15;
    int wm = wid >> 2, wn = wid & 3;

    f32x4 acc[8][4];
#pragma unroll
    for (int i = 0; i < 8; i++)
#pragma unroll
        for (int j = 0; j < 4; j++) acc[i][j] = (f32x4){0.f, 0.f, 0.f, 0.f};
    core256(Q, K, &As[0][0], &As[1][0], &Bs[0][0], &Bs[1][0], acc, tid);

    // Epilogue: per (i,rg) row, chunk-max over the 64 cols (4 j-frags x 16
    // l15 lanes), P in fp8, stats write. No LDS use -> no barrier needed.
    u32* Pt = Pbuf + ((size_t)((b * 16 + mblk) * 16 + nblk)) * 16384;
    int ch = nblk * 4 + wn;
    float2* Sp = statsP + ((size_t)(b * 64 + ch)) * 4096;
    int mbase = mblk * 256 + wm * 128;
#pragma unroll
    for (int i = 0; i < 8; i++) {
        u32x4 pk;
#pragma unroll
        for (int rg = 0; rg < 4; rg++) {
            float v0 = acc[i][0][rg], v1 = acc[i][1][rg];
            float v2 = acc[i][2][rg], v3 = acc[i][3][rg];
            float Mt = fmaxf(fmaxf(v0, v1), fmaxf(v2, v3));
            Mt = dpp_max16(Mt);  // uniform over the 16 l15 lanes
            float e8 = Mt - 8.0f;  // x256 pre-scale for fp8 range
            float p0 = fexp2(v0 - e8), p1 = fexp2(v1 - e8);
            float p2 = fexp2(v2 - e8), p3 = fexp2(v3 - e8);
            pk[rg] = fp8x4_pack(p0, p1, p2, p3);
            float L = dpp_sum16(p0 + p1 + p2 + p3);
            if (l15 == 0)
                Sp[mbase + i * 16 + quad * 4 + rg] =
                    make_float2(Mt, L * 0.00390625f);  // true L_ch
        }
        *(u32x4*)&Pt[i * 2048 + tid * 4] = pk;
    }
}

// ---------------------------------------------------------------------------
// Weighted column sums with FUSED cstat (r24): each block recomputes the
// c = M + log2(Z) values for its 512 rows into LDS (16x redundancy across
// the 16 nblk blocks sharing an mgrp, fed from hot L2; math verified
// numerically by the r23 mega kernel's S4, which passed with identical
// absmax). Kills the separate reduce_stats2 launch.
// S[n] += sum_m P_fp8[m,n] * exp2(Mt[m]-8-c[m]). F-SKIP (2^-58): dropped
// mass/col <= 4096*256*2^-58 = 2^-38, scale err <= 3.6e-3.
// grid (nblk=16, mgrp=8 (2 mblks each), b=2), 512 threads: thread tid holds
// the SAME (m,n) cells it wrote in pass 1.
// ---------------------------------------------------------------------------
__global__ __launch_bounds__(512) void colsum(
    const u32* __restrict__ Pbuf, const float2* __restrict__ statsP,
    float* __restrict__ Sg) {
    __shared__ float cs[512];
    int tid = threadIdx.x, lane = tid & 63, wid = tid >> 6;
    int quad = lane >> 4, l15 = lane & 15;
    int wm = wid >> 2, wn = wid & 3;
    int nblk = blockIdx.x, mgrp = blockIdx.y, b = blockIdx.z;
    // Fused cstat: rows [mgrp*512, mgrp*512+512) for this batch.
    {
        int m = mgrp * 512 + tid;
        const float2* sp = statsP + (size_t)b * 64 * 4096 + m;
        float M = -INFINITY;
#pragma unroll 4
        for (int ch = 0; ch < 64; ch++) M = fmaxf(M, sp[(size_t)ch * 4096].x);
        float Z = 0.f;
#pragma unroll 4
        for (int ch = 0; ch < 64; ch++) {
            float2 p = sp[(size_t)ch * 4096];
            Z += p.y * fexp2(p.x - M);
        }
        cs[tid] = M + __log2f(Z);
    }
    __syncthreads();
    int ch = nblk * 4 + wn;
    const float2* Sp = statsP + ((size_t)(b * 64 + ch)) * 4096;
    float cp[4] = {0.f, 0.f, 0.f, 0.f};
    for (int mb = 0; mb < 2; mb++) {
        int mblk = mgrp * 2 + mb;
        const u32* Pt =
            Pbuf + ((size_t)((b * 16 + mblk) * 16 + nblk)) * 16384;
#pragma unroll
        for (int i = 0; i < 8; i++) {
            int r0 = mblk * 256 + wm * 128 + i * 16 + quad * 4;
            float4 s01 = *(const float4*)&Sp[r0];      // (M0,L0,M1,L1)
            float4 s23 = *(const float4*)&Sp[r0 + 2];  // (M2,L2,M3,L3)
            int rl0 = mb * 256 + wm * 128 + i * 16 + quad * 4;
            float4 cv = *(const float4*)&cs[rl0];
            float fv[4] = {fexp2(s01.x - 8.0f - cv.x),
                           fexp2(s01.z - 8.0f - cv.y),
                           fexp2(s23.x - 8.0f - cv.z),
                           fexp2(s23.z - 8.0f - cv.w)};
            float fm = fmaxf(fmaxf(fv[0], fv[1]), fmaxf(fv[2], fv[3]));
            if (fm > 3.469446951953614e-18f) {  // 2^-58: see header comment
                u32x4 e4 = *(const u32x4*)&Pt[i * 2048 + tid * 4];
#pragma unroll
                for (int rg = 0; rg < 4; rg++) {
                    u32 e = e4[rg];
                    cp[0] += FP8_DEC(e, 0) * fv[rg];
                    cp[1] += FP8_DEC(e, 1) * fv[rg];
                    cp[2] += FP8_DEC(e, 2) * fv[rg];
                    cp[3] += FP8_DEC(e, 3) * fv[rg];
                }
            }
        }
    }
#pragma unroll
    for (int j = 0; j < 4; j++) {
        float s = cp[j];
        s += __shfl_xor(s, 16);
        s += __shfl_xor(s, 32);
        if (lane < 16)
            atomicAdd(&Sg[b * 4096 + nblk * 256 + wn * 64 + j * 16 + l15], s);
    }
}

// ---------------------------------------------------------------------------
// Final: out = relu(BN((V*rowscale) . Wo^T + bo)) + X  (fp32 out)
// 64x128 tiles, grid (128, 4). m0 in [0,8192) == flat (b,m).
// ---------------------------------------------------------------------------
__global__ __launch_bounds__(256) void gemm_final(
    const u16* __restrict__ A, const u16* __restrict__ Bt,
    const float* __restrict__ Sg, const float* __restrict__ bo,
    const float* __restrict__ g, const float* __restrict__ bb,
    const float* __restrict__ mean, const float* __restrict__ var,
    const float* __restrict__ X, float* __restrict__ out) {
    __shared__ __align__(16) u16 As[4096];
    __shared__ __align__(16) u16 Bs[8192];
    int tid = threadIdx.x;
    int m0 = blockIdx.x * 64, n0 = blockIdx.y * 128;
    f32x4 acc[2][4];
#pragma unroll
    for (int i = 0; i < 2; i++)
#pragma unroll
        for (int j = 0; j < 4; j++) acc[i][j] = (f32x4){0.f, 0.f, 0.f, 0.f};
    gemm512_r64(A + (size_t)m0 * 512, Bt + (size_t)n0 * 512, As, Bs, acc, tid);
    int lane = tid & 63, quad = lane >> 4, l15 = lane & 15;
    int wm = tid >> 7, wn = (tid >> 6) & 1;
    float sc[2][4];
#pragma unroll
    for (int i = 0; i < 2; i++) {
        float4 s = *(const float4*)&Sg[m0 + wm * 32 + i * 16 + quad * 4];
        float v[4] = {s.x, s.y, s.z, s.w};
#pragma unroll
        for (int rg = 0; rg < 4; rg++) sc[i][rg] = v[rg] / (1e-9f + v[rg]);
    }
#pragma unroll
    for (int j = 0; j < 4; j++) {
        int n = n0 + wn * 64 + j * 16 + l15;
        float aj = rsqrtf(var[n] + 1e-5f) * g[n];
        float cj = bb[n] - mean[n] * aj;
        float bj = bo[n];
#pragma unroll
        for (int i = 0; i < 2; i++)
#pragma unroll
            for (int rg = 0; rg < 4; rg++) {
                int m = m0 + wm * 32 + i * 16 + quad * 4 + rg;
                float x = acc[i][j][rg] * sc[i][rg] + bj;
                float y = x * aj + cj;
                out[(size_t)m * 512 + n] = fmaxf(y, 0.f) + X[(size_t)m * 512 + n];
            }
    }
}

// ---------------------------------------------------------------------------
extern "C" void kernel_launch(void* const* d_in, const int* in_sizes, int n_in,
                              void* d_out, int out_size, void* d_ws, size_t ws_size,
                              hipStream_t stream) {
    const float* X  = (const float*)d_in[0];
    const float* Wq = (const float*)d_in[1];
    const float* Wk = (const float*)d_in[2];
    const float* Wv = (const float*)d_in[3];
    const float* Wo = (const float*)d_in[4];
    const float* bq = (const float*)d_in[5];
    const float* bk = (const float*)d_in[6];
    const float* bv = (const float*)d_in[7];
    const float* bo = (const float*)d_in[8];
    const float* g    = (const float*)d_in[9];
    const float* bb   = (const float*)d_in[10];
    const float* mean = (const float*)d_in[11];
    const float* var  = (const float*)d_in[12];
    float* out = (float*)d_out;

    char* ws = (char*)d_ws;
    u16* Xb  = (u16*)(ws + 0);                    // 8 MB
    u16* Wqt = (u16*)(ws + 8388608);              // 4x512KB (Wq,Wk,Wv,Wo)
    u16* Wot = (u16*)(ws + 9961472);
    u16* Qb  = (u16*)(ws + 10485760);             // Q,K,V contiguous 3x8MB
    u16* Kb  = (u16*)(ws + 18874368);
    u16* Vb  = (u16*)(ws + 27262976);
    float2* statsP = (float2*)(ws + 35651584);    // [b][64][4096] f2 = 4 MB
    float* Sg      = (float*)(ws + 39845888);     // 32 KB
    u32* Pbuf      = (u32*)(ws + 39911424);       // 32 MB fp8 P

    prep<<<5121, 256, 0, stream>>>(X, Wq, Wk, Wv, Wo, Xb, Wqt, Wqt + 262144,
                                   Wqt + 524288, Wot, Sg);
    gemm_qkv<<<dim3(32, 2, 3), 512, 0, stream>>>(Xb, Wqt, bq, bk, bv, Qb);
    attn_pass1p<<<dim3(16, 16, 2), 512, 0, stream>>>(Qb, Kb, statsP, Pbuf);
    colsum<<<dim3(16, 8, 2), 512, 0, stream>>>(Pbuf, statsP, Sg);
    gemm_final<<<dim3(128, 4), 256, 0, stream>>>(Vb, Wot, Sg, bo, g, bb, mean, var,
                                                 X, out);
}

// Round 10
// 200.637 us; speedup vs baseline: 1.8139x; 1.0133x over previous
//
#include <hip/hip_runtime.h>
#include <hip/hip_bf16.h>

typedef unsigned short u16;
typedef unsigned int u32;
typedef __attribute__((ext_vector_type(8))) short short8;
typedef __attribute__((ext_vector_type(4))) float f32x4;
typedef __attribute__((ext_vector_type(4))) unsigned int u32x4;

__device__ __forceinline__ u16 f2bf(float f) {
    union { float f; unsigned u; } v; v.f = f;
    unsigned r = v.u + 0x7fffu + ((v.u >> 16) & 1u);
    return (u16)(r >> 16);
}

__device__ __forceinline__ float fexp2(float x) {
#if __has_builtin(__builtin_amdgcn_exp2f)
    return __builtin_amdgcn_exp2f(x);
#else
    return __expf(x * 0.6931471805599453f);
#endif
}

// ---------------------------------------------------------------------------
// DPP 16-lane butterfly (r15): masks {1,2,7,15} are GF(2)-independent ->
// valid butterfly over each contiguous 16-lane row.
// ---------------------------------------------------------------------------
template <int CTRL>
__device__ __forceinline__ float fdpp(float x) {
    int xi = __builtin_bit_cast(int, x);
    int r = __builtin_amdgcn_update_dpp(0, xi, CTRL, 0xF, 0xF, true);
    return __builtin_bit_cast(float, r);
}
__device__ __forceinline__ float dpp_max16(float m) {
    m = fmaxf(m, fdpp<0xB1>(m));   // xor 1
    m = fmaxf(m, fdpp<0x4E>(m));   // xor 2
    m = fmaxf(m, fdpp<0x141>(m));  // xor 7 (row_half_mirror)
    m = fmaxf(m, fdpp<0x140>(m));  // xor 15 (row_mirror)
    return m;
}
__device__ __forceinline__ float dpp_sum16(float s) {
    s += fdpp<0xB1>(s);
    s += fdpp<0x4E>(s);
    s += fdpp<0x141>(s);
    s += fdpp<0x140>(s);
    return s;
}

// ---------------------------------------------------------------------------
// fp8 e4m3 pack/unpack (P pre-scaled x256; r9-r13 absmax 0.078).
// ---------------------------------------------------------------------------
#if __has_builtin(__builtin_amdgcn_cvt_pk_fp8_f32) && \
    __has_builtin(__builtin_amdgcn_cvt_f32_fp8)
#define FP8_HW 1
#else
#define FP8_HW 0
#endif

#if !FP8_HW
__device__ __forceinline__ u32 sw_fp8(float x) {  // x in [0, 448]
    union { float f; u32 u; } v; v.f = x;
    int E = (int)(v.u >> 23) - 127;
    if (x < 0.001953125f) return 0;
    if (E < -6) return (u32)(x * 512.0f + 0.5f);
    u32 m = v.u & 0x7fffffu;
    u32 r = (m + 0x80000u) >> 20;
    u32 bits = ((u32)(E + 7) << 3) + r;
    return bits > 0x7eu ? 0x7eu : bits;
}
__device__ __forceinline__ float sw_fp8d(u32 b) {
    u32 e = (b >> 3) & 15u, m = b & 7u;
    if (e == 0) return (float)m * 0.001953125f;
    union { u32 u; float f; } v; v.u = ((e + 120u) << 23) | (m << 20);
    return v.f;
}
#endif

__device__ __forceinline__ u32 fp8x4_pack(float p0, float p1, float p2, float p3) {
#if FP8_HW
    u32 v = (u32)__builtin_amdgcn_cvt_pk_fp8_f32(p0, p1, 0, false);
    v = (u32)__builtin_amdgcn_cvt_pk_fp8_f32(p2, p3, (int)v, true);
    return v;
#else
    return sw_fp8(p0) | (sw_fp8(p1) << 8) | (sw_fp8(p2) << 16) | (sw_fp8(p3) << 24);
#endif
}

#if FP8_HW
#define FP8_DEC(v, s) __builtin_amdgcn_cvt_f32_fp8((int)(v), (s))
#else
#define FP8_DEC(v, s) sw_fp8d(((v) >> ((s) * 8)) & 0xffu)
#endif

// async 16B global->LDS DMA (m97 pattern).
__device__ __forceinline__ void async_cp16(const u16* g, u16* l) {
    __builtin_amdgcn_global_load_lds(
        (const __attribute__((address_space(1))) void*)g,
        (__attribute__((address_space(3))) void*)l, 16, 0, 0);
}

__device__ __forceinline__ short8 mfma_ld(const u16* base, int off) {
    return *(const short8*)&base[off];
}

// ---------------------------------------------------------------------------
// Staging helpers for the 8-phase 256x256 core (T3+T4 schedule).
// Half-tiles: A-half(ih) = wins wm'*16 + ih*8 + [0,8); B-half(jh) = wins
// wn'*8 + jh*4 + [0,4). Each wave stages 2 wins (1 KiB each) per half.
// LDS dest is wave-uniform base + lane*16 (global_load_lds constraint);
// the XOR swizzle lives in the per-lane GLOBAL source address (m173 pattern).
// ---------------------------------------------------------------------------
__device__ __forceinline__ void stage_half_A(const u16* __restrict__ Q,
                                             u16* dst, int kn, int half,
                                             int wid, int srow, int scol) {
#pragma unroll
    for (int c = 0; c < 2; c++) {
        int win = (wid >> 2) * 16 + half * 8 + (wid & 3) * 2 + c;
        async_cp16(Q + (size_t)(win * 8 + srow) * 512 + kn + scol,
                   dst + win * 512);
    }
}
__device__ __forceinline__ void stage_half_B(const u16* __restrict__ K,
                                             u16* dst, int kn, int half,
                                             int wid, int srow, int scol) {
#pragma unroll
    for (int c = 0; c < 2; c++) {
        int win = (wid >> 1) * 8 + half * 4 + (wid & 1) * 2 + c;
        async_cp16(K + (size_t)(win * 8 + srow) * 512 + kn + scol,
                   dst + win * 512);
    }
}

// ---------------------------------------------------------------------------
// Shared 256x256x512 8-phase core -- SESSION-FINAL VERIFIED OPTIMUM of this
// structure family. Experiments that regressed and were reverted:
//  - r19 1-barrier/phase: symmetric waves have no role-split; skew+setprio
//    created convoys (52->65us, unstable).
//  - r21 shifted register pipeline: +112 live VGPRs -> ~9MB/dispatch scratch
//    spill (WRITE_SIZE 36.9->46.1MB), 47.8->49.5us.
//  - r22 4-way launch split: underfill (128 blocks on 256 CUs), +40us.
//  - r23 cooperative mega-fusion: grid.sync serialization + idle stages,
//    262us single dispatch.
//  - r24 cstat-fused colsum: 16x redundant recompute > saved launch (+2.8us).
// Structure: 8 waves (2Mx4N), BK=64, 128 KiB LDS dbuf, counted vmcnt (never
// 0 in loop): half-tiles of kt+1 staged at A0,B0@p0, B1@p1, A1@p2; waits
// vmcnt(6)@p1, vmcnt(2)@p3. Gray-code phases (0,0)->(0,1)->(1,1)->(1,0),
// register-held B-halves (24 ds_read_b128/kt/wave, the minimum for this
// tile). A.B^T into acc[8][4]; acc (i,j,rg) = C row m0+wm*128+i*16+quad*4+rg,
// col n0+wn*64+j*16+l15. Operating point: ~675 TF (MfmaUtil ~27%) -- the
// K=512 short-pipeline plateau (8 kt-steps can't amortize prologue/barrier
// overhead the way K=4096 structures do). Untried levers with upside but
// real regression risk: 32x32x16 MFMA fragment rewrite; qkv 256-block fill.
// ---------------------------------------------------------------------------
__device__ __forceinline__ void core256(const u16* __restrict__ A,
                                        const u16* __restrict__ B,
                                        u16* As0, u16* As1,
                                        u16* Bs0, u16* Bs1,
                                        f32x4 acc[8][4], int tid) {
    int lane = tid & 63, wid = tid >> 6;
    int quad = lane >> 4, l15 = lane & 15;
    int wm = wid >> 2, wn = wid & 3;
    int Gw = lane ^ ((lane >> 3) & 7);
    int srow = Gw >> 3, scol = (Gw & 7) * 8;
    int rl = l15 & 7, winl = l15 >> 3;
    int Pr[2];
#pragma unroll
    for (int h = 0; h < 2; h++)
        Pr[h] = (rl * 8 + ((quad + h * 4) ^ rl)) * 8;

    // Prologue: stage tile 0 fully, single full drain (only one in core).
    stage_half_A(A, As0, 0, 0, wid, srow, scol);
    stage_half_B(B, Bs0, 0, 0, wid, srow, scol);
    stage_half_B(B, Bs0, 0, 1, wid, srow, scol);
    stage_half_A(A, As0, 0, 1, wid, srow, scol);
    asm volatile("s_waitcnt vmcnt(0)" ::: "memory");
    __builtin_amdgcn_s_barrier();
    asm volatile("" ::: "memory");

    for (int kt = 0; kt < 8; ++kt) {
        const u16* Ac = (kt & 1) ? As1 : As0;
        const u16* Bc = (kt & 1) ? Bs1 : Bs0;
        u16* An = (kt & 1) ? As0 : As1;
        u16* Bn = (kt & 1) ? Bs0 : Bs1;
        int kn = (kt + 1) * 64;
        bool pf = (kt < 7);
        short8 af[4][2], bf0[2][2], bf1[2][2];
#pragma unroll
        for (int ph = 0; ph < 4; ++ph) {
            // Gray code: (ih,jh) = (0,0),(0,1),(1,1),(1,0)
            const int ih = ph >> 1;
            const int jh = (ph ^ (ph >> 1)) & 1;
            if (ph == 0) {
#pragma unroll
                for (int h = 0; h < 2; h++)
#pragma unroll
                    for (int ii = 0; ii < 4; ii++)
                        af[ii][h] = mfma_ld(
                            Ac, (wm * 16 + ii * 2 + winl) * 512 + Pr[h]);
#pragma unroll
                for (int h = 0; h < 2; h++)
#pragma unroll
                    for (int jj = 0; jj < 2; jj++)
                        bf0[jj][h] = mfma_ld(
                            Bc, (wn * 8 + jj * 2 + winl) * 512 + Pr[h]);
            } else if (ph == 1) {
#pragma unroll
                for (int h = 0; h < 2; h++)
#pragma unroll
                    for (int jj = 0; jj < 2; jj++)
                        bf1[jj][h] = mfma_ld(
                            Bc, (wn * 8 + 4 + jj * 2 + winl) * 512 + Pr[h]);
            } else if (ph == 2) {
#pragma unroll
                for (int h = 0; h < 2; h++)
#pragma unroll
                    for (int ii = 0; ii < 4; ii++)
                        af[ii][h] = mfma_ld(
                            Ac, (wm * 16 + 8 + ii * 2 + winl) * 512 + Pr[h]);
            }
            if (pf) {
                if (ph == 0) {
                    stage_half_A(A, An, kn, 0, wid, srow, scol);
                    stage_half_B(B, Bn, kn, 0, wid, srow, scol);
                } else if (ph == 1) {
                    stage_half_B(B, Bn, kn, 1, wid, srow, scol);
                } else if (ph == 2) {
                    stage_half_A(A, An, kn, 1, wid, srow, scol);
                }
            }
            if (ph == 1) {
                if (pf) asm volatile("s_waitcnt vmcnt(6)" ::: "memory");
                else    asm volatile("s_waitcnt vmcnt(0)" ::: "memory");
            }
            if (ph == 3) asm volatile("s_waitcnt vmcnt(2)" ::: "memory");
            asm volatile("" ::: "memory");
            __builtin_amdgcn_s_barrier();
            asm volatile("s_waitcnt lgkmcnt(0)" ::: "memory");
            __builtin_amdgcn_s_setprio(1);
            if (jh == 0) {
#pragma unroll
                for (int h = 0; h < 2; h++)
#pragma unroll
                    for (int ii = 0; ii < 4; ii++)
#pragma unroll
                        for (int jj = 0; jj < 2; jj++)
                            acc[ih * 4 + ii][jj] =
                                __builtin_amdgcn_mfma_f32_16x16x32_bf16(
                                    af[ii][h], bf0[jj][h],
                                    acc[ih * 4 + ii][jj], 0, 0, 0);
            } else {
#pragma unroll
                for (int h = 0; h < 2; h++)
#pragma unroll
                    for (int ii = 0; ii < 4; ii++)
#pragma unroll
                        for (int jj = 0; jj < 2; jj++)
                            acc[ih * 4 + ii][2 + jj] =
                                __builtin_amdgcn_mfma_f32_16x16x32_bf16(
                                    af[ii][h], bf1[jj][h],
                                    acc[ih * 4 + ii][2 + jj], 0, 0, 0);
            }
            __builtin_amdgcn_s_setprio(0);
            asm volatile("" ::: "memory");
            __builtin_amdgcn_s_barrier();
            asm volatile("" ::: "memory");
        }
    }
}

// 64x128x512 variant (A 64 rows). As: 4096 u16, Bs: 8192 u16.
__device__ __forceinline__ void gemm512_r64(const u16* __restrict__ A,
                                            const u16* __restrict__ B,
                                            u16* As, u16* Bs,
                                            f32x4 acc[2][4], int tid) {
    const int lane = tid & 63, w = tid >> 6;
    const int quad = lane >> 4, l15 = lane & 15;
    const int wm = tid >> 7, wn = (tid >> 6) & 1;
    const int Gw = lane ^ ((lane >> 3) & 7);
    const int srow = Gw >> 3;
    const int scol = (Gw & 7) * 8;
    const int rl = l15 & 7;
    const int winl = l15 >> 3;
    int Pr[2];
#pragma unroll
    for (int h = 0; h < 2; h++)
        Pr[h] = (rl * 8 + ((quad + h * 4) ^ rl)) * 8;
    const int winA0 = (wm * 32) >> 3, winB0 = (wn * 64) >> 3;
    for (int k0 = 0; k0 < 512; k0 += 64) {
        __syncthreads();
#pragma unroll
        for (int t = 0; t < 2; t++) {
            int win = w * 2 + t;
            async_cp16(A + (size_t)(win * 8 + srow) * 512 + k0 + scol,
                       As + win * 512);
        }
#pragma unroll
        for (int t = 0; t < 4; t++) {
            int win = w * 4 + t;
            async_cp16(B + (size_t)(win * 8 + srow) * 512 + k0 + scol,
                       Bs + win * 512);
        }
        __syncthreads();
#pragma unroll
        for (int h = 0; h < 2; h++) {
            short8 af[2], bfr[4];
#pragma unroll
            for (int i = 0; i < 2; i++)
                af[i] = mfma_ld(As, (winA0 + i * 2 + winl) * 512 + Pr[h]);
#pragma unroll
            for (int j = 0; j < 4; j++)
                bfr[j] = mfma_ld(Bs, (winB0 + j * 2 + winl) * 512 + Pr[h]);
#pragma unroll
            for (int i = 0; i < 2; i++)
#pragma unroll
                for (int j = 0; j < 4; j++)
                    acc[i][j] = __builtin_amdgcn_mfma_f32_16x16x32_bf16(
                        af[i], bfr[j], acc[i][j], 0, 0, 0);
        }
    }
}

// ---------------------------------------------------------------------------
// Fused prep: [0,4096) convert X->bf16; [4096,5120) transpose weights;
// 5120: zero Sg (per-launch, graph-safe).
// ---------------------------------------------------------------------------
__global__ void prep(const float* __restrict__ X, const float* __restrict__ W0,
                     const float* __restrict__ W1, const float* __restrict__ W2,
                     const float* __restrict__ W3, u16* __restrict__ Xb,
                     u16* __restrict__ T0, u16* __restrict__ T1,
                     u16* __restrict__ T2, u16* __restrict__ T3,
                     float* __restrict__ Sg) {
    __shared__ float tile[32][33];
    int id = blockIdx.x, tid = threadIdx.x;
    if (id == 5120) {
        float4 z = {0.f, 0.f, 0.f, 0.f};
#pragma unroll
        for (int t = 0; t < 8; t++) ((float4*)Sg)[tid + t * 256] = z;
        return;
    }
    if (id < 4096) {
        int idx = (id * 256 + tid) * 4;
        float4 v = *(const float4*)&X[idx];
        ushort4 o;
        o.x = f2bf(v.x); o.y = f2bf(v.y); o.z = f2bf(v.z); o.w = f2bf(v.w);
        *(ushort4*)&Xb[idx] = o;
        return;
    }
    int t = id - 4096;
    int z = t >> 8, rem = t & 255;
    int bo_ = (rem & 15) * 32, bi = (rem >> 4) * 32;
    const float* src; u16* dst;
    switch (z) {
        case 0: src = W0; dst = T0; break;
        case 1: src = W1; dst = T1; break;
        case 2: src = W2; dst = T2; break;
        default: src = W3; dst = T3; break;
    }
    int tx = tid & 31, ty = tid >> 5;
#pragma unroll
    for (int s = 0; s < 4; s++) {
        int i = bi + ty + s * 8;
        tile[ty + s * 8][tx] = src[i * 512 + bo_ + tx];
    }
    __syncthreads();
#pragma unroll
    for (int s = 0; s < 4; s++) {
        int o = bo_ + ty + s * 8;
        dst[o * 512 + bi + tx] = f2bf(tile[tx][ty + s * 8]);
    }
}

// ---------------------------------------------------------------------------
// Fused QKV projection (256x256 8-phase core). Grid (32, 2, 3), 512 threads.
// z==0 (Q) scaled by log2(e) -> base-2 score domain.
// ---------------------------------------------------------------------------
__global__ __launch_bounds__(512, 2) void gemm_qkv(
    const u16* __restrict__ Xb, const u16* __restrict__ Wall,
    const float* __restrict__ bq, const float* __restrict__ bk,
    const float* __restrict__ bv, u16* __restrict__ Qall) {
    __shared__ __align__(16) u16 As[2][16384];
    __shared__ __align__(16) u16 Bs[2][16384];
    int tid = threadIdx.x;
    int m0 = blockIdx.x * 256, n0 = blockIdx.y * 256, z = blockIdx.z;
    const u16* A = Xb + (size_t)m0 * 512;
    const u16* B = Wall + (size_t)z * 262144 + (size_t)n0 * 512;
    f32x4 acc[8][4];
#pragma unroll
    for (int i = 0; i < 8; i++)
#pragma unroll
        for (int j = 0; j < 4; j++) acc[i][j] = (f32x4){0.f, 0.f, 0.f, 0.f};
    core256(A, B, &As[0][0], &As[1][0], &Bs[0][0], &Bs[1][0], acc, tid);

    const float* bias = (z == 0) ? bq : (z == 1) ? bk : bv;
    const float qs = (z == 0) ? 1.44269504088896340736f : 1.0f;
    u16* C = Qall + (size_t)z * 4194304;
    int lane = tid & 63, wid = tid >> 6;
    int quad = lane >> 4, l15 = lane & 15;
    int wm = wid >> 2, wn = wid & 3;
#pragma unroll
    for (int j = 0; j < 4; j++) {
        int n = n0 + wn * 64 + j * 16 + l15;
        float bvv = bias[n];
#pragma unroll
        for (int i = 0; i < 8; i++)
#pragma unroll
            for (int rg = 0; rg < 4; rg++) {
                int m = m0 + wm * 128 + i * 16 + quad * 4 + rg;
                C[(size_t)m * 512 + n] = f2bf((acc[i][j][rg] + bvv) * qs);
            }
    }
}

// ---------------------------------------------------------------------------
// Pass 1 (256x256 8-phase core + softmax epilogue). Epilogue: per (i,rg)
// row, chunk-max over 64 cols via DPP butterfly, P = exp2(s - Mt + 8) fp8x4
// in Pbuf[i][tid][rg] (dwordx4), stats (Mt, L/256).
// Grid (16, 16, 2), 512 threads.
// ---------------------------------------------------------------------------
__global__ __launch_bounds__(512, 2) void attn_pass1p(
    const u16* __restrict__ Qb, const u16* __restrict__ Kb,
    float2* __restrict__ statsP, u32* __restrict__ Pbuf) {
    __shared__ __align__(16) u16 As[2][16384];
    __shared__ __align__(16) u16 Bs[2][16384];
    int tid = threadIdx.x;
    int mblk = blockIdx.x, nblk = blockIdx.y, b = blockIdx.z;
    const u16* Q = Qb + ((size_t)(b * 4096 + mblk * 256)) * 512;
    const u16* K = Kb + ((size_t)(b * 4096 + nblk * 256)) * 512;
    int lane = tid & 63, wid = tid >> 6;
    int quad = lane >> 4, l15 = lane & 15;
    int wm = wid >> 2, wn = wid & 3;

    f32x4 acc[8][4];
#pragma unroll
    for (int i = 0; i < 8; i++)
#pragma unroll
        for (int j = 0; j < 4; j++) acc[i][j] = (f32x4){0.f, 0.f, 0.f, 0.f};
    core256(Q, K, &As[0][0], &As[1][0], &Bs[0][0], &Bs[1][0], acc, tid);

    // Epilogue: per (i,rg) row, chunk-max over the 64 cols (4 j-frags x 16
    // l15 lanes), P in fp8, stats write. No LDS use -> no barrier needed.
    u32* Pt = Pbuf + ((size_t)((b * 16 + mblk) * 16 + nblk)) * 16384;
    int ch = nblk * 4 + wn;
    float2* Sp = statsP + ((size_t)(b * 64 + ch)) * 4096;
    int mbase = mblk * 256 + wm * 128;
#pragma unroll
    for (int i = 0; i < 8; i++) {
        u32x4 pk;
#pragma unroll
        for (int rg = 0; rg < 4; rg++) {
            float v0 = acc[i][0][rg], v1 = acc[i][1][rg];
            float v2 = acc[i][2][rg], v3 = acc[i][3][rg];
            float Mt = fmaxf(fmaxf(v0, v1), fmaxf(v2, v3));
            Mt = dpp_max16(Mt);  // uniform over the 16 l15 lanes
            float e8 = Mt - 8.0f;  // x256 pre-scale for fp8 range
            float p0 = fexp2(v0 - e8), p1 = fexp2(v1 - e8);
            float p2 = fexp2(v2 - e8), p3 = fexp2(v3 - e8);
            pk[rg] = fp8x4_pack(p0, p1, p2, p3);
            float L = dpp_sum16(p0 + p1 + p2 + p3);
            if (l15 == 0)
                Sp[mbase + i * 16 + quad * 4 + rg] =
                    make_float2(Mt, L * 0.00390625f);  // true L_ch
        }
        *(u32x4*)&Pt[i * 2048 + tid * 4] = pk;
    }
}

// ---------------------------------------------------------------------------
// c = M + log2(Z) per row. Separate kernel is the measured optimum (r10:
// fusing into colsum = 64x redundancy, +10us; r24: 16x-redundant LDS fusion
// +2.8us; launches in this graph-captured harness are ~free per r22/r23).
// grid 32 x 256.
// ---------------------------------------------------------------------------
__global__ void reduce_stats2(const float2* __restrict__ statsP,
                              float* __restrict__ cstat) {
    int t = blockIdx.x * 256 + threadIdx.x;
    int b = t >> 12, m = t & 4095;
    const float2* sp = statsP + (size_t)b * 64 * 4096 + m;
    float M = -INFINITY;
#pragma unroll 4
    for (int ch = 0; ch < 64; ch++) M = fmaxf(M, sp[(size_t)ch * 4096].x);
    float Z = 0.f;
#pragma unroll 4
    for (int ch = 0; ch < 64; ch++) {
        float2 p = sp[(size_t)ch * 4096];
        Z += p.y * fexp2(p.x - M);
    }
    cstat[t] = M + __log2f(Z);
}

// ---------------------------------------------------------------------------
// Weighted column sums (Pbuf layout [i][tid][rg] -> dwordx4 loads):
// S[n] += sum_m P_fp8[m,n] * exp2(Mt[m]-8-c[m]). F-SKIP (2^-58): dropped
// mass/col <= 4096*256*2^-58 = 2^-38, scale err <= 3.6e-3.
// grid (nblk=16, mgrp=8 (2 mblks each), b=2), 512 threads: thread tid holds
// the SAME (m,n) cells it wrote in pass 1.
// ---------------------------------------------------------------------------
__global__ __launch_bounds__(512) void colsum(
    const u32* __restrict__ Pbuf, const float2* __restrict__ statsP,
    const float* __restrict__ cstat, float* __restrict__ Sg) {
    int tid = threadIdx.x, lane = tid & 63, wid = tid >> 6;
    int quad = lane >> 4, l15 = lane & 15;
    int wm = wid >> 2, wn = wid & 3;
    int nblk = blockIdx.x, mgrp = blockIdx.y, b = blockIdx.z;
    int ch = nblk * 4 + wn;
    const float2* Sp = statsP + ((size_t)(b * 64 + ch)) * 4096;
    const float* Cp = cstat + (size_t)b * 4096;
    float cp[4] = {0.f, 0.f, 0.f, 0.f};
    for (int mb = 0; mb < 2; mb++) {
        int mblk = mgrp * 2 + mb;
        const u32* Pt =
            Pbuf + ((size_t)((b * 16 + mblk) * 16 + nblk)) * 16384;
#pragma unroll
        for (int i = 0; i < 8; i++) {
            int r0 = mblk * 256 + wm * 128 + i * 16 + quad * 4;
            float4 s01 = *(const float4*)&Sp[r0];      // (M0,L0,M1,L1)
            float4 s23 = *(const float4*)&Sp[r0 + 2];  // (M2,L2,M3,L3)
            float4 cv = *(const float4*)&Cp[r0];
            float fv[4] = {fexp2(s01.x - 8.0f - cv.x),
                           fexp2(s01.z - 8.0f - cv.y),
                           fexp2(s23.x - 8.0f - cv.z),
                           fexp2(s23.z - 8.0f - cv.w)};
            float fm = fmaxf(fmaxf(fv[0], fv[1]), fmaxf(fv[2], fv[3]));
            if (fm > 3.469446951953614e-18f) {  // 2^-58: see header comment
                u32x4 e4 = *(const u32x4*)&Pt[i * 2048 + tid * 4];
#pragma unroll
                for (int rg = 0; rg < 4; rg++) {
                    u32 e = e4[rg];
                    cp[0] += FP8_DEC(e, 0) * fv[rg];
                    cp[1] += FP8_DEC(e, 1) * fv[rg];
                    cp[2] += FP8_DEC(e, 2) * fv[rg];
                    cp[3] += FP8_DEC(e, 3) * fv[rg];
                }
            }
        }
    }
#pragma unroll
    for (int j = 0; j < 4; j++) {
        float s = cp[j];
        s += __shfl_xor(s, 16);
        s += __shfl_xor(s, 32);
        if (lane < 16)
            atomicAdd(&Sg[b * 4096 + nblk * 256 + wn * 64 + j * 16 + l15], s);
    }
}

// ---------------------------------------------------------------------------
// Final: out = relu(BN((V*rowscale) . Wo^T + bo)) + X  (fp32 out)
// 64x128 tiles, grid (128, 4). m0 in [0,8192) == flat (b,m).
// ---------------------------------------------------------------------------
__global__ __launch_bounds__(256) void gemm_final(
    const u16* __restrict__ A, const u16* __restrict__ Bt,
    const float* __restrict__ Sg, const float* __restrict__ bo,
    const float* __restrict__ g, const float* __restrict__ bb,
    const float* __restrict__ mean, const float* __restrict__ var,
    const float* __restrict__ X, float* __restrict__ out) {
    __shared__ __align__(16) u16 As[4096];
    __shared__ __align__(16) u16 Bs[8192];
    int tid = threadIdx.x;
    int m0 = blockIdx.x * 64, n0 = blockIdx.y * 128;
    f32x4 acc[2][4];
#pragma unroll
    for (int i = 0; i < 2; i++)
#pragma unroll
        for (int j = 0; j < 4; j++) acc[i][j] = (f32x4){0.f, 0.f, 0.f, 0.f};
    gemm512_r64(A + (size_t)m0 * 512, Bt + (size_t)n0 * 512, As, Bs, acc, tid);
    int lane = tid & 63, quad = lane >> 4, l15 = lane & 15;
    int wm = tid >> 7, wn = (tid >> 6) & 1;
    float sc[2][4];
#pragma unroll
    for (int i = 0; i < 2; i++) {
        float4 s = *(const float4*)&Sg[m0 + wm * 32 + i * 16 + quad * 4];
        float v[4] = {s.x, s.y, s.z, s.w};
#pragma unroll
        for (int rg = 0; rg < 4; rg++) sc[i][rg] = v[rg] / (1e-9f + v[rg]);
    }
#pragma unroll
    for (int j = 0; j < 4; j++) {
        int n = n0 + wn * 64 + j * 16 + l15;
        float aj = rsqrtf(var[n] + 1e-5f) * g[n];
        float cj = bb[n] - mean[n] * aj;
        float bj = bo[n];
#pragma unroll
        for (int i = 0; i < 2; i++)
#pragma unroll
            for (int rg = 0; rg < 4; rg++) {
                int m = m0 + wm * 32 + i * 16 + quad * 4 + rg;
                float x = acc[i][j][rg] * sc[i][rg] + bj;
                float y = x * aj + cj;
                out[(size_t)m * 512 + n] = fmaxf(y, 0.f) + X[(size_t)m * 512 + n];
            }
    }
}

// ---------------------------------------------------------------------------
extern "C" void kernel_launch(void* const* d_in, const int* in_sizes, int n_in,
                              void* d_out, int out_size, void* d_ws, size_t ws_size,
                              hipStream_t stream) {
    const float* X  = (const float*)d_in[0];
    const float* Wq = (const float*)d_in[1];
    const float* Wk = (const float*)d_in[2];
    const float* Wv = (const float*)d_in[3];
    const float* Wo = (const float*)d_in[4];
    const float* bq = (const float*)d_in[5];
    const float* bk = (const float*)d_in[6];
    const float* bv = (const float*)d_in[7];
    const float* bo = (const float*)d_in[8];
    const float* g    = (const float*)d_in[9];
    const float* bb   = (const float*)d_in[10];
    const float* mean = (const float*)d_in[11];
    const float* var  = (const float*)d_in[12];
    float* out = (float*)d_out;

    char* ws = (char*)d_ws;
    u16* Xb  = (u16*)(ws + 0);                    // 8 MB
    u16* Wqt = (u16*)(ws + 8388608);              // 4x512KB (Wq,Wk,Wv,Wo)
    u16* Wot = (u16*)(ws + 9961472);
    u16* Qb  = (u16*)(ws + 10485760);             // Q,K,V contiguous 3x8MB
    u16* Kb  = (u16*)(ws + 18874368);
    u16* Vb  = (u16*)(ws + 27262976);
    float2* statsP = (float2*)(ws + 35651584);    // [b][64][4096] f2 = 4 MB
    float* Sg      = (float*)(ws + 39845888);     // 32 KB
    float* cstat   = (float*)(ws + 39878656);     // 32 KB
    u32* Pbuf      = (u32*)(ws + 39911424);       // 32 MB fp8 P

    prep<<<5121, 256, 0, stream>>>(X, Wq, Wk, Wv, Wo, Xb, Wqt, Wqt + 262144,
                                   Wqt + 524288, Wot, Sg);
    gemm_qkv<<<dim3(32, 2, 3), 512, 0, stream>>>(Xb, Wqt, bq, bk, bv, Qb);
    attn_pass1p<<<dim3(16, 16, 2), 512, 0, stream>>>(Qb, Kb, statsP, Pbuf);
    reduce_stats2<<<32, 256, 0, stream>>>(statsP, cstat);
    colsum<<<dim3(16, 8, 2), 512, 0, stream>>>(Pbuf, statsP, cstat, Sg);
    gemm_final<<<dim3(128, 4), 256, 0, stream>>>(Vb, Wot, Sg, bo, g, bb, mean, var,
                                                 X, out);
}